// Round 7
// baseline (1937.927 us; speedup 1.0000x reference)
//
#include <hip/hip_runtime.h>
#include <stdint.h>

#define NN 50000
#define EE 1250000
#define BB 500
#define NBY 4883      // ceil(EE/256)
#define CHUNK 196     // ceil(NN/256) for scan partitions
#define BN_EPS 1e-5f

#define NTB 8192      // table intervals; 8193 knots
#define XLO (-12.0f)
#define XHI (12.0f)
#define XSC ((float)NTB / (XHI - XLO))   // knots at XLO + i/XSC
#define DXT ((XHI - XLO) / (float)NTB)
#define TPMAX 8191.999f

using u16 = unsigned short;
using u32 = unsigned int;

__device__ __forceinline__ float bf2f(u16 v) { return __uint_as_float(((u32)v) << 16); }
__device__ __forceinline__ u16 f2bf(float f) {
    u32 u = __float_as_uint(f);
    return (u16)((u + 0x7fffu + ((u >> 16) & 1u)) >> 16);
}
__device__ __forceinline__ u32 pk2(float a, float b) { return (u32)f2bf(a) | ((u32)f2bf(b) << 16); }
__device__ __forceinline__ float sp(float z) {   // softplus = max(z,0)+log1p(exp(-|z|))
    float t = __expf(-fabsf(z));
    return fmaxf(z, 0.f) + __logf(1.f + t);
}

// ---------------- workspace layout (~65 MB) ----------------
constexpr size_t OFF_ESD  = 0;                                    // int4 [E] {src, et, x_bits, 0}
constexpr size_t OFF_ROWP = OFF_ESD + (size_t)EE * 16;            // row_ptr [N+1]
constexpr size_t OFF_HA   = (OFF_ROWP + (size_t)(NN + 1) * 4 + 255) & ~(size_t)255;
constexpr size_t OFF_HB   = OFF_HA + (size_t)NN * 64 * 4;
constexpr size_t OFF_ZB   = OFF_HB + (size_t)NN * 64 * 4;         // [N,32]
constexpr size_t OFF_YTAB = OFF_ZB + (size_t)NN * 32 * 4;         // f32 [NTB+1][64]
constexpr size_t OFF_PTAB = OFF_YTAB + (size_t)(NTB + 1) * 64 * 4;// u32 [NTB][64] bf16 pairs (affined)
constexpr size_t OFF_W2T  = OFF_PTAB + (size_t)NTB * 64 * 4;      // w_d2 transposed f32 [64][64]
constexpr size_t OFF_B2F  = OFF_W2T + 4096 * 4;
constexpr size_t OFF_AW   = OFF_B2F + 256;
constexpr size_t OFF_CW   = OFF_AW + 256;
constexpr size_t OFF_MX   = OFF_CW + 256;
constexpr size_t OFF_SC2  = OFF_MX + 256;
constexpr size_t OFF_SH2  = OFF_SC2 + 256;
constexpr size_t OFF_PSUM = OFF_SH2 + 256;                        // [256] int
constexpr size_t OFF_PBASE= OFF_PSUM + 1024;                      // [256] int
constexpr size_t OFF_W1T  = OFF_PBASE + 1024;                     // f32 [128][64] (w_o1^T)
constexpr size_t OFF_W2O  = OFF_W1T + 8192 * 4;                   // f32 [64][32]  (w_o2^T)
constexpr size_t OFF_W3T  = OFF_W2O + 2048 * 4;                   // f32 [32][128] (w_o3^T)
// zero region (one memset): hist | cursor | hg | xstat | sty | 5 stat slots | bin hist (c,s,q)
constexpr size_t OFF_HIST = (OFF_W3T + 4096 * 4 + 255) & ~(size_t)255;
constexpr size_t OFF_CUR  = OFF_HIST + (size_t)NN * 4;
constexpr size_t OFF_HG   = OFF_CUR + (size_t)NN * 4;
constexpr size_t OFF_XSTAT= OFF_HG + (size_t)BB * 64 * 4;         // 2 doubles
constexpr size_t OFF_STY  = OFF_XSTAT + 16;                       // 128 doubles
constexpr size_t OFF_FST  = OFF_STY + 128 * 8;
constexpr size_t OFF_BH   = OFF_FST + 5 * 128 * 8;                // f32 [3][NTB]
constexpr size_t ZERO_END = OFF_BH + 3 * NTB * 4;
constexpr size_t ZERO_BYTES = ZERO_END - OFF_HIST;

// ---------------- prep kernels ----------------
__global__ void k_w2prep(const float* __restrict__ w2, const float* __restrict__ b2,
                         float* __restrict__ w2T, float* __restrict__ b2f) {
    int idx = blockIdx.x * 256 + threadIdx.x;            // 4096
    int hin = idx >> 6, ho = idx & 63;
    w2T[idx] = w2[ho * 64 + hin];                        // w2T[hin][ho] = w_d2[ho][hin]
    if (idx < 64) b2f[idx] = b2[idx];
}

// transpose head weights for coalesced lane=outfeature GEMVs
__global__ void k_otprep(const float* __restrict__ w1, const float* __restrict__ w2,
                         const float* __restrict__ w3, float* __restrict__ w1T,
                         float* __restrict__ w2T2, float* __restrict__ w3T) {
    int idx = blockIdx.x * 256 + threadIdx.x;            // 14336
    if (idx < 8192) {                                    // w_o1 [64][128] -> w1T[j][ho]
        int j = idx >> 6, ho = idx & 63;
        w1T[idx] = w1[ho * 128 + j];
    } else if (idx < 8192 + 2048) {                      // w_o2 [32][64] -> w2T2[j][ho]
        int t = idx - 8192;
        int j = t >> 5, ho = t & 31;
        w2T2[t] = w2[ho * 64 + j];
    } else if (idx < 8192 + 2048 + 4096) {               // w_o3 [128][32] -> w3T[j][jo]
        int t = idx - 8192 - 2048;
        int j = t >> 7, jo = t & 127;
        w3T[t] = w3[jo * 32 + j];
    }
}

__global__ void k_xstats(const float* __restrict__ x, double* __restrict__ xstat) {
    __shared__ float ls[256], lq[256];
    float s = 0, q = 0;
    for (int i = blockIdx.x * 256 + threadIdx.x; i < EE; i += gridDim.x * 256) {
        float v = x[i]; s += v; q += v * v;
    }
    ls[threadIdx.x] = s; lq[threadIdx.x] = q; __syncthreads();
    for (int off = 128; off > 0; off >>= 1) {
        if (threadIdx.x < off) { ls[threadIdx.x] += ls[threadIdx.x + off]; lq[threadIdx.x] += lq[threadIdx.x + off]; }
        __syncthreads();
    }
    if (threadIdx.x == 0) { atomicAdd(&xstat[0], (double)ls[0]); atomicAdd(&xstat[1], (double)lq[0]); }
}

// fused: dst histogram (for CSR sort) + x-bin statistics (for BN2 moments)
__global__ void k_hist(const int* __restrict__ dstv, const float* __restrict__ x,
                       int* __restrict__ hist, float* __restrict__ bhc,
                       float* __restrict__ bhs, float* __restrict__ bhq) {
    int e = blockIdx.x * 256 + threadIdx.x;
    if (e >= EE) return;
    atomicAdd(&hist[dstv[e]], 1);
    float tp = fminf(fmaxf((x[e] - XLO) * XSC, 0.f), TPMAX);
    int i = (int)tp; float f = tp - (float)i;
    atomicAdd(&bhc[i], 1.f);
    atomicAdd(&bhs[i], f);
    atomicAdd(&bhq[i], f * f);
}

__global__ void k_scanA(const int* __restrict__ hist, int* __restrict__ psum) {
    __shared__ int ls[256];
    int t = threadIdx.x, idx = blockIdx.x * CHUNK + t;
    ls[t] = (t < CHUNK && idx < NN) ? hist[idx] : 0; __syncthreads();
    for (int off = 128; off > 0; off >>= 1) {
        if (t < off) ls[t] += ls[t + off];
        __syncthreads();
    }
    if (t == 0) psum[blockIdx.x] = ls[0];
}

__global__ void k_scanB(const int* __restrict__ psum, int* __restrict__ pbase, int* __restrict__ row_ptr) {
    __shared__ int ls[256];
    int t = threadIdx.x, v = psum[t];
    ls[t] = v; __syncthreads();
    for (int off = 1; off < 256; off <<= 1) {
        int a = ls[t]; int b = (t >= off) ? ls[t - off] : 0; __syncthreads();
        ls[t] = a + b; __syncthreads();
    }
    pbase[t] = ls[t] - v;
    if (t == 0) row_ptr[NN] = EE;
}

__global__ void k_scanC(const int* __restrict__ hist, const int* __restrict__ pbase, int* __restrict__ row_ptr) {
    __shared__ int ls[256];
    int t = threadIdx.x, idx = blockIdx.x * CHUNK + t;
    int v = (t < CHUNK && idx < NN) ? hist[idx] : 0;
    ls[t] = v; __syncthreads();
    for (int off = 1; off < 256; off <<= 1) {
        int a = ls[t]; int b = (t >= off) ? ls[t - off] : 0; __syncthreads();
        ls[t] = a + b; __syncthreads();
    }
    if (t < CHUNK && idx < NN) row_ptr[idx] = pbase[blockIdx.x] + ls[t] - v;
}

__global__ void k_prep2(const double* __restrict__ xstat, const float* __restrict__ w1,
                        const float* __restrict__ g1, const float* __restrict__ be1,
                        float* __restrict__ Aw, float* __restrict__ Cw, float* __restrict__ mxp) {
    int f = threadIdx.x;  // 64
    double mx = xstat[0] / (double)EE;
    double vx = xstat[1] / (double)EE - mx * mx; if (vx < 0) vx = 0;
    float w = w1[f];
    Aw[f] = w * rsqrtf((float)vx * w * w + BN_EPS) * g1[f];
    Cw[f] = be1[f];
    if (f == 0) mxp[0] = (float)mx;
}

// build y(x) table: wave-per-knot, lane = output feature; d1 via shuffle broadcast
__global__ void __launch_bounds__(256) k_ytab(
        const float* __restrict__ Aw, const float* __restrict__ Cw, const float* __restrict__ mxp,
        const float* __restrict__ w2T, const float* __restrict__ b2f, float* __restrict__ ytab) {
    int lane = threadIdx.x & 63;
    int idx = blockIdx.x * 4 + (threadIdx.x >> 6);       // knot id
    if (idx > NTB) return;
    float xi = XLO + (float)idx * DXT;
    float t = xi - mxp[0];
    float d1L = sp(fmaf(Aw[lane], t, Cw[lane]));         // lane holds d1[lane]
    float y = b2f[lane];
    #pragma unroll
    for (int hin = 0; hin < 64; hin++) {
        float d1 = __shfl(d1L, hin, 64);
        y = fmaf(d1, w2T[hin * 64 + lane], y);
    }
    ytab[(size_t)idx * 64 + lane] = y;
}

// BN2 moments from bin statistics: exact for the interpolated y.
// Sum(y)   = (c-s)A + sB ; Sum(y^2) = (c-2s+q)A^2 + 2(s-q)AB + qB^2  per bin.
__global__ void __launch_bounds__(256) k_moments(
        const float* __restrict__ ytab, const float* __restrict__ bhc,
        const float* __restrict__ bhs, const float* __restrict__ bhq,
        double* __restrict__ sty) {
    int lane = threadIdx.x & 63;
    int gw = blockIdx.x * 4 + (threadIdx.x >> 6);        // 256 waves total (64 blocks)
    float m1 = 0, m2 = 0;
    int i0 = gw * (NTB / 256);
    for (int i = i0; i < i0 + NTB / 256; ++i) {
        float c = bhc[i], s = bhs[i], q = bhq[i];
        float A = ytab[(size_t)i * 64 + lane];
        float B = ytab[(size_t)(i + 1) * 64 + lane];
        m1 += (c - s) * A + s * B;
        m2 += (c - 2.f * s + q) * A * A + 2.f * (s - q) * A * B + q * B * B;
    }
    __shared__ float lsS[256], lsQ[256];
    lsS[threadIdx.x] = m1; lsQ[threadIdx.x] = m2; __syncthreads();
    if (threadIdx.x < 128) {
        int ff = threadIdx.x & 63; bool isq = threadIdx.x >= 64;
        float acc = 0;
        #pragma unroll
        for (int j = 0; j < 4; j++) acc += isq ? lsQ[j * 64 + ff] : lsS[j * 64 + ff];
        atomicAdd(&sty[threadIdx.x], (double)acc);
    }
}

__global__ void k_ysc(const double* __restrict__ sty, const float* __restrict__ g2,
                      const float* __restrict__ be2, float* __restrict__ sc2, float* __restrict__ sh2) {
    int f = threadIdx.x;  // 64
    double m = sty[f] / (double)EE;
    double var = sty[64 + f] / (double)EE - m * m; if (var < 0) var = 0;
    float rstd = rsqrtf((float)var + BN_EPS);
    float sc = rstd * g2[f];
    sc2[f] = sc;
    sh2[f] = be2[f] - (float)m * sc;
}

// pack affined bf16 pair table: ptab[i][f] = {aff(ytab[i][f]), aff(ytab[i+1][f])}
__global__ void k_ypack(const float* __restrict__ ytab, const float* __restrict__ sc2,
                        const float* __restrict__ sh2, u32* __restrict__ ptab) {
    int tid = blockIdx.x * 256 + threadIdx.x;            // NTB*64
    int f = tid & 63;
    float sc = sc2[f], sh = sh2[f];
    float a = fmaf(ytab[tid], sc, sh);
    float b = fmaf(ytab[tid + 64], sc, sh);
    ptab[tid] = pk2(a, b);
}

// counting-sort edges: write packed {src, et, x} into dst-sorted position
__global__ void __launch_bounds__(256) k_scatter(
        const float* __restrict__ x, const int* __restrict__ src, const int* __restrict__ dstv,
        const int* __restrict__ etv, const int* __restrict__ row_ptr, int* __restrict__ cursor,
        int4* __restrict__ esd) {
    int e = blockIdx.x * 256 + threadIdx.x;
    if (e >= EE) return;
    int d = dstv[e];
    int p = row_ptr[d] + atomicAdd(&cursor[d], 1);
    int4 v; v.x = src[e]; v.y = etv[e]; v.z = __float_as_int(x[e]); v.w = 0;
    esd[p] = v;
}

__device__ __forceinline__ float edge_term(int4 ed, int lane, const u32* __restrict__ ptab,
                                           const float* __restrict__ emb) {
    float xv = __int_as_float(ed.z);
    float tp = fminf(fmaxf((xv - XLO) * XSC, 0.f), TPMAX);
    int i = (int)tp; float f = tp - (float)i;
    u32 pr = ptab[i * 64 + lane];
    float a = bf2f((u16)(pr & 0xffff)), b = bf2f((u16)(pr >> 16));
    float y = fmaf(f, b - a, a);                         // BN2-affined y
    return y * emb[(size_t)ed.y * 64 + lane];
}

// wave-per-node aggregation, lane = feature; generic h input; unroll-4
__global__ void __launch_bounds__(256) k_agg(
        const float* __restrict__ h, const int4* __restrict__ esd, const int* __restrict__ row_ptr,
        const u32* __restrict__ ptab, const float* __restrict__ emb, float* __restrict__ hpre) {
    int lane = threadIdx.x & 63;
    int n = __builtin_amdgcn_readfirstlane((int)(blockIdx.x * 4 + (threadIdx.x >> 6)));
    if (n >= NN) return;
    int p0 = row_ptr[n], p1 = row_ptr[n + 1];
    float acc = 0.f;
    int p = p0;
    for (; p + 4 <= p1; p += 4) {
        int4 e0 = esd[p], e1 = esd[p + 1], e2 = esd[p + 2], e3 = esd[p + 3];
        float h0 = h[(size_t)e0.x * 64 + lane];
        float h1 = h[(size_t)e1.x * 64 + lane];
        float h2 = h[(size_t)e2.x * 64 + lane];
        float h3 = h[(size_t)e3.x * 64 + lane];
        float a0 = edge_term(e0, lane, ptab, emb);
        float a1 = edge_term(e1, lane, ptab, emb);
        float a2 = edge_term(e2, lane, ptab, emb);
        float a3 = edge_term(e3, lane, ptab, emb);
        acc += sp(h0 + a0) + sp(h1 + a1) + sp(h2 + a2) + sp(h3 + a3);
    }
    for (; p < p1; ++p) {
        int4 e0 = esd[p];
        float h0 = h[(size_t)e0.x * 64 + lane];
        acc += sp(h0 + edge_term(e0, lane, ptab, emb));
    }
    size_t o = (size_t)n * 64 + lane;
    hpre[o] = acc + h[o];
}

// gconv1 variant: h comes from node_emb[node_type] (L1-resident)
__global__ void __launch_bounds__(256) k_agg0(
        const int* __restrict__ nt, const float* __restrict__ nemb, const int4* __restrict__ esd,
        const int* __restrict__ row_ptr, const u32* __restrict__ ptab,
        const float* __restrict__ emb, float* __restrict__ hpre) {
    int lane = threadIdx.x & 63;
    int n = __builtin_amdgcn_readfirstlane((int)(blockIdx.x * 4 + (threadIdx.x >> 6)));
    if (n >= NN) return;
    int p0 = row_ptr[n], p1 = row_ptr[n + 1];
    float acc = 0.f;
    int p = p0;
    for (; p + 4 <= p1; p += 4) {
        int4 e0 = esd[p], e1 = esd[p + 1], e2 = esd[p + 2], e3 = esd[p + 3];
        float h0 = nemb[(size_t)nt[e0.x] * 64 + lane];
        float h1 = nemb[(size_t)nt[e1.x] * 64 + lane];
        float h2 = nemb[(size_t)nt[e2.x] * 64 + lane];
        float h3 = nemb[(size_t)nt[e3.x] * 64 + lane];
        float a0 = edge_term(e0, lane, ptab, emb);
        float a1 = edge_term(e1, lane, ptab, emb);
        float a2 = edge_term(e2, lane, ptab, emb);
        float a3 = edge_term(e3, lane, ptab, emb);
        acc += sp(h0 + a0) + sp(h1 + a1) + sp(h2 + a2) + sp(h3 + a3);
    }
    for (; p < p1; ++p) {
        int4 e0 = esd[p];
        float h0 = nemb[(size_t)nt[e0.x] * 64 + lane];
        acc += sp(h0 + edge_term(e0, lane, ptab, emb));
    }
    hpre[(size_t)n * 64 + lane] = acc + nemb[(size_t)nt[n] * 64 + lane];
}

// per-feature mean/var partials over [rows, C] (C = 1<<logC), f64 atomics
__global__ void k_fstats(const float* __restrict__ v, int rows, int logC, double* __restrict__ stat) {
    int C = 1 << logC;
    int f = threadIdx.x & (C - 1);
    int r0 = threadIdx.x >> logC;
    int rpb = 256 >> logC;
    float s = 0, q = 0;
    for (int r = blockIdx.x * rpb + r0; r < rows; r += gridDim.x * rpb) {
        float val = v[(size_t)r * C + f];
        s += val; q += val * val;
    }
    __shared__ float lsS[256], lsQ[256];
    lsS[threadIdx.x] = s; lsQ[threadIdx.x] = q; __syncthreads();
    if (threadIdx.x < C) {
        float ss = 0, qq = 0;
        for (int j = 0; j < rpb; j++) { ss += lsS[j * C + threadIdx.x]; qq += lsQ[j * C + threadIdx.x]; }
        atomicAdd(&stat[threadIdx.x], (double)ss);
        atomicAdd(&stat[C + threadIdx.x], (double)qq);
    }
}

__global__ void k_bn(const float* __restrict__ in, float* __restrict__ out,
                     const double* __restrict__ stat, const float* __restrict__ g,
                     const float* __restrict__ be, int rows, int logC, int act) {
    int C = 1 << logC;
    size_t total = (size_t)rows << logC;
    size_t i = (size_t)blockIdx.x * 256 + threadIdx.x;
    if (i >= total) return;
    int f = (int)(i & (C - 1));
    double m = stat[f] / (double)rows;
    double var = stat[C + f] / (double)rows - m * m; if (var < 0) var = 0;
    float rstd = rsqrtf((float)var + BN_EPS);
    float val = (in[i] - (float)m) * rstd * g[f] + be[f];
    out[i] = act ? sp(val) : val;
}

__global__ void k_hglobal(const float* __restrict__ h, const int* __restrict__ batch, float* __restrict__ hg) {
    int idx = blockIdx.x * 256 + threadIdx.x;            // N*64
    int n = idx >> 6, f = idx & 63;
    atomicAdd(&hg[(size_t)batch[n] * 64 + f], h[idx]);
}

// head GEMV 1: lane = output feature; coalesced w1T rows; input broadcast via shfl
__global__ void __launch_bounds__(256) k_o1(
        const float* __restrict__ h, const float* __restrict__ hg, const int* __restrict__ batch,
        const float* __restrict__ w1T, const float* __restrict__ b1, float* __restrict__ z1) {
    int lane = threadIdx.x & 63;
    int n = __builtin_amdgcn_readfirstlane((int)(blockIdx.x * 4 + (threadIdx.x >> 6)));
    if (n >= NN) return;
    int b = batch[n];
    float hl = h[(size_t)n * 64 + lane];
    float gl = hg[(size_t)b * 64 + lane];
    float acc = b1[lane];
    #pragma unroll
    for (int j = 0; j < 64; j++)
        acc = fmaf(__shfl(hl, j, 64), w1T[j * 64 + lane], acc);
    #pragma unroll
    for (int j = 0; j < 64; j++)
        acc = fmaf(__shfl(gl, j, 64), w1T[(64 + j) * 64 + lane], acc);
    z1[(size_t)n * 64 + lane] = acc;
}

// head GEMV 2: 2 nodes per wave, lane = (node half, output feature 0..31)
__global__ void __launch_bounds__(256) k_o2(
        const float* __restrict__ o1v, const float* __restrict__ w2T2,
        const float* __restrict__ b2, float* __restrict__ z2) {
    int tid = threadIdx.x;
    int lane = tid & 63;
    int ho = lane & 31;
    int base = lane & 32;                                // my half's lane base
    int n = blockIdx.x * 8 + (tid >> 5);
    if (n >= NN) return;
    float hl = o1v[(size_t)n * 64 + ho];
    float hh = o1v[(size_t)n * 64 + 32 + ho];
    float acc = b2[ho];
    #pragma unroll
    for (int j = 0; j < 32; j++)
        acc = fmaf(__shfl(hl, base + j, 64), w2T2[j * 32 + ho], acc);
    #pragma unroll
    for (int j = 0; j < 32; j++)
        acc = fmaf(__shfl(hh, base + j, 64), w2T2[(32 + j) * 32 + ho], acc);
    z2[(size_t)n * 32 + ho] = acc;
}

// head GEMV 3: 2 waves per node (jo = 0..127), coalesced w3T rows
__global__ void __launch_bounds__(256) k_o3(
        const float* __restrict__ o2v, const float* __restrict__ w3T,
        const float* __restrict__ b3, float* __restrict__ outp) {
    int gtid = blockIdx.x * 256 + threadIdx.x;           // N*128
    int lane = threadIdx.x & 63;
    int w = gtid >> 6;
    int n = w >> 1;
    int jo = ((w & 1) << 6) + lane;
    if (n >= NN) return;
    float zl = o2v[(size_t)n * 32 + (lane & 31)];
    float acc = b3[jo];
    #pragma unroll
    for (int j = 0; j < 32; j++)
        acc = fmaf(__shfl(zl, j, 64), w3T[j * 128 + jo], acc);
    size_t dsti = (jo < 64) ? ((size_t)n * 64 + jo) : ((size_t)NN * 64 + (size_t)n * 64 + (jo - 64));
    outp[dsti] = acc;                                    // f32 output
}

extern "C" void kernel_launch(void* const* d_in, const int* in_sizes, int n_in,
                              void* d_out, int out_size, void* d_ws, size_t ws_size,
                              hipStream_t stream) {
    const float* x        = (const float*)d_in[0];
    const int* node_type  = (const int*)d_in[1];
    const int* edge_type  = (const int*)d_in[2];
    const int* edge_index = (const int*)d_in[3];
    const int* batch      = (const int*)d_in[4];
    const float* node_emb = (const float*)d_in[5];
    const float* edge_emb = (const float*)d_in[6];
    const float* w_d1 = (const float*)d_in[7];  const float* b_d1 = (const float*)d_in[8];
    const float* g_d1 = (const float*)d_in[9];  const float* be_d1 = (const float*)d_in[10];
    const float* w_d2 = (const float*)d_in[11]; const float* b_d2 = (const float*)d_in[12];
    const float* g_d2 = (const float*)d_in[13]; const float* be_d2 = (const float*)d_in[14];
    const float* g_c1 = (const float*)d_in[15]; const float* be_c1 = (const float*)d_in[16];
    const float* g_c2 = (const float*)d_in[17]; const float* be_c2 = (const float*)d_in[18];
    const float* g_c3 = (const float*)d_in[19]; const float* be_c3 = (const float*)d_in[20];
    const float* w_o1 = (const float*)d_in[21]; const float* b_o1 = (const float*)d_in[22];
    const float* g_o1 = (const float*)d_in[23]; const float* be_o1 = (const float*)d_in[24];
    const float* w_o2 = (const float*)d_in[25]; const float* b_o2 = (const float*)d_in[26];
    const float* g_o2 = (const float*)d_in[27]; const float* be_o2 = (const float*)d_in[28];
    const float* w_o3 = (const float*)d_in[29]; const float* b_o3 = (const float*)d_in[30];
    (void)b_d1;  // cancels inside BN1 (mean subtraction removes per-feature shift)
    const int* src  = edge_index;
    const int* dstv = edge_index + EE;

    char* ws = (char*)d_ws;
    int4*  esd     = (int4*)(ws + OFF_ESD);
    int*   row_ptr = (int*)(ws + OFF_ROWP);
    float* hA   = (float*)(ws + OFF_HA);
    float* hB   = (float*)(ws + OFF_HB);
    float* zb   = (float*)(ws + OFF_ZB);
    float* ytab = (float*)(ws + OFF_YTAB);
    u32*   ptab = (u32*)(ws + OFF_PTAB);
    float* w2T  = (float*)(ws + OFF_W2T);
    float* b2f  = (float*)(ws + OFF_B2F);
    float* Aw   = (float*)(ws + OFF_AW);
    float* Cw   = (float*)(ws + OFF_CW);
    float* mxp  = (float*)(ws + OFF_MX);
    float* sc2  = (float*)(ws + OFF_SC2);
    float* sh2  = (float*)(ws + OFF_SH2);
    int*   psum = (int*)(ws + OFF_PSUM);
    int*   pbase= (int*)(ws + OFF_PBASE);
    float* w1T  = (float*)(ws + OFF_W1T);
    float* w2T2 = (float*)(ws + OFF_W2O);
    float* w3T  = (float*)(ws + OFF_W3T);
    int*   hist   = (int*)(ws + OFF_HIST);
    int*   cursor = (int*)(ws + OFF_CUR);
    float* hg     = (float*)(ws + OFF_HG);
    double* xstat = (double*)(ws + OFF_XSTAT);
    double* sty   = (double*)(ws + OFF_STY);
    double* fst   = (double*)(ws + OFF_FST);
    float* bhc = (float*)(ws + OFF_BH);
    float* bhs = bhc + NTB;
    float* bhq = bhc + 2 * NTB;
    double* st0 = fst;          double* st1 = fst + 128;  double* st2 = fst + 256;
    double* st3 = fst + 384;    double* st4 = fst + 512;

    hipMemsetAsync(ws + OFF_HIST, 0, ZERO_BYTES, stream);

    k_w2prep<<<16, 256, 0, stream>>>(w_d2, b_d2, w2T, b2f);
    k_otprep<<<56, 256, 0, stream>>>(w_o1, w_o2, w_o3, w1T, w2T2, w3T);
    k_xstats<<<512, 256, 0, stream>>>(x, xstat);
    k_hist<<<NBY, 256, 0, stream>>>(dstv, x, hist, bhc, bhs, bhq);
    k_scanA<<<256, 256, 0, stream>>>(hist, psum);
    k_scanB<<<1, 256, 0, stream>>>(psum, pbase, row_ptr);
    k_scanC<<<256, 256, 0, stream>>>(hist, pbase, row_ptr);
    k_prep2<<<1, 64, 0, stream>>>(xstat, w_d1, g_d1, be_d1, Aw, Cw, mxp);
    k_ytab<<<(NTB + 1 + 3) / 4, 256, 0, stream>>>(Aw, Cw, mxp, w2T, b2f, ytab);
    k_scatter<<<NBY, 256, 0, stream>>>(x, src, dstv, edge_type, row_ptr, cursor, esd);
    k_moments<<<64, 256, 0, stream>>>(ytab, bhc, bhs, bhq, sty);
    k_ysc<<<1, 64, 0, stream>>>(sty, g_d2, be_d2, sc2, sh2);
    k_ypack<<<NTB * 64 / 256, 256, 0, stream>>>(ytab, sc2, sh2, ptab);
    // gconv 1 (h from node_emb[node_type], L1-resident)
    k_agg0<<<12500, 256, 0, stream>>>(node_type, node_emb, esd, row_ptr, ptab, edge_emb, hB);
    k_fstats<<<1024, 256, 0, stream>>>(hB, NN, 6, st0);
    k_bn<<<12500, 256, 0, stream>>>(hB, hB, st0, g_c1, be_c1, NN, 6, 1);
    // gconv 2
    k_agg<<<12500, 256, 0, stream>>>(hB, esd, row_ptr, ptab, edge_emb, hA);
    k_fstats<<<1024, 256, 0, stream>>>(hA, NN, 6, st1);
    k_bn<<<12500, 256, 0, stream>>>(hA, hA, st1, g_c2, be_c2, NN, 6, 1);
    // gconv 3 (no activation)
    k_agg<<<12500, 256, 0, stream>>>(hA, esd, row_ptr, ptab, edge_emb, hB);
    k_fstats<<<1024, 256, 0, stream>>>(hB, NN, 6, st2);
    k_bn<<<12500, 256, 0, stream>>>(hB, hB, st2, g_c3, be_c3, NN, 6, 0);
    // global pool + head
    k_hglobal<<<12500, 256, 0, stream>>>(hB, batch, hg);
    k_o1<<<12500, 256, 0, stream>>>(hB, hg, batch, w1T, b_o1, hA);
    k_fstats<<<1024, 256, 0, stream>>>(hA, NN, 6, st3);
    k_bn<<<12500, 256, 0, stream>>>(hA, hA, st3, g_o1, be_o1, NN, 6, 1);
    k_o2<<<6250, 256, 0, stream>>>(hA, w2T2, b_o2, zb);
    k_fstats<<<1024, 256, 0, stream>>>(zb, NN, 5, st4);
    k_bn<<<6250, 256, 0, stream>>>(zb, zb, st4, g_o2, be_o2, NN, 5, 1);
    k_o3<<<25000, 256, 0, stream>>>(zb, w3T, b_o3, (float*)d_out);
    (void)in_sizes; (void)n_in; (void)out_size; (void)ws_size;
}

// Round 8
// 1258.628 us; speedup vs baseline: 1.5397x; 1.5397x over previous
//
#include <hip/hip_runtime.h>
#include <stdint.h>

#define NN 50000
#define EE 1250000
#define BB 500
#define NBY 4883      // ceil(EE/256)
#define CHUNK 196     // ceil(NN/256) for scan partitions
#define BN_EPS 1e-5f

#define NTB 8192      // table intervals; 8193 knots
#define XLO (-12.0f)
#define XHI (12.0f)
#define XSC ((float)NTB / (XHI - XLO))   // knots at XLO + i/XSC
#define DXT ((XHI - XLO) / (float)NTB)
#define TPMAX 8191.999f

using u16 = unsigned short;
using u32 = unsigned int;
using u64 = unsigned long long;

__device__ __forceinline__ float bf2f(u16 v) { return __uint_as_float(((u32)v) << 16); }
__device__ __forceinline__ u16 f2bf(float f) {
    u32 u = __float_as_uint(f);
    return (u16)((u + 0x7fffu + ((u >> 16) & 1u)) >> 16);
}
__device__ __forceinline__ u32 pk2(float a, float b) { return (u32)f2bf(a) | ((u32)f2bf(b) << 16); }
__device__ __forceinline__ float sp(float z) {   // softplus = max(z,0)+log1p(exp(-|z|))
    float t = __expf(-fabsf(z));
    return fmaxf(z, 0.f) + __logf(1.f + t);
}

// ---------------- workspace layout (~65 MB) ----------------
constexpr size_t OFF_ESD  = 0;                                    // int4 [E] {src, et, x_bits, 0}
constexpr size_t OFF_ROWP = OFF_ESD + (size_t)EE * 16;            // row_ptr [N+1]
constexpr size_t OFF_HA   = (OFF_ROWP + (size_t)(NN + 1) * 4 + 255) & ~(size_t)255;
constexpr size_t OFF_HB   = OFF_HA + (size_t)NN * 64 * 4;
constexpr size_t OFF_ZB   = OFF_HB + (size_t)NN * 64 * 4;         // [N,32]
constexpr size_t OFF_YTAB = OFF_ZB + (size_t)NN * 32 * 4;         // f32 [NTB+1][64]
constexpr size_t OFF_PTAB = OFF_YTAB + (size_t)(NTB + 1) * 64 * 4;// u32 [NTB][64] bf16 pairs (affined)
constexpr size_t OFF_W2T  = OFF_PTAB + (size_t)NTB * 64 * 4;      // w_d2 transposed f32 [64][64]
constexpr size_t OFF_B2F  = OFF_W2T + 4096 * 4;
constexpr size_t OFF_AW   = OFF_B2F + 256;
constexpr size_t OFF_CW   = OFF_AW + 256;
constexpr size_t OFF_MX   = OFF_CW + 256;
constexpr size_t OFF_SC2  = OFF_MX + 256;
constexpr size_t OFF_SH2  = OFF_SC2 + 256;
constexpr size_t OFF_PSUM = OFF_SH2 + 256;                        // [256] int
constexpr size_t OFF_PBASE= OFF_PSUM + 1024;                      // [256] int
constexpr size_t OFF_W1T  = OFF_PBASE + 1024;                     // f32 [128][64] (w_o1^T)
constexpr size_t OFF_W2O  = OFF_W1T + 8192 * 4;                   // f32 [64][32]  (w_o2^T)
constexpr size_t OFF_W3T  = OFF_W2O + 2048 * 4;                   // f32 [32][128] (w_o3^T)
// zero region (one memset): hist | cursor | hg | xstat | sty | 5 stat slots | bin hists
constexpr size_t OFF_HIST = (OFF_W3T + 4096 * 4 + 255) & ~(size_t)255;
constexpr size_t OFF_CUR  = OFF_HIST + (size_t)NN * 4;
constexpr size_t OFF_HG   = OFF_CUR + (size_t)NN * 4;
constexpr size_t OFF_XSTAT= OFF_HG + (size_t)BB * 64 * 4;         // 2 doubles
constexpr size_t OFF_STY  = OFF_XSTAT + 16;                       // 128 doubles
constexpr size_t OFF_FST  = OFF_STY + 128 * 8;
constexpr size_t OFF_BC   = OFF_FST + 5 * 128 * 8;                // u32 [NTB]
constexpr size_t OFF_BS   = OFF_BC + NTB * 4;                     // u64 [NTB]
constexpr size_t OFF_BQ   = OFF_BS + NTB * 8;                     // u64 [NTB]
constexpr size_t ZERO_END = OFF_BQ + NTB * 8;
constexpr size_t ZERO_BYTES = ZERO_END - OFF_HIST;

// ---------------- prep kernels ----------------
__global__ void k_w2prep(const float* __restrict__ w2, const float* __restrict__ b2,
                         float* __restrict__ w2T, float* __restrict__ b2f) {
    int idx = blockIdx.x * 256 + threadIdx.x;            // 4096
    int hin = idx >> 6, ho = idx & 63;
    w2T[idx] = w2[ho * 64 + hin];                        // w2T[hin][ho] = w_d2[ho][hin]
    if (idx < 64) b2f[idx] = b2[idx];
}

// transpose head weights for coalesced lane=outfeature GEMVs
__global__ void k_otprep(const float* __restrict__ w1, const float* __restrict__ w2,
                         const float* __restrict__ w3, float* __restrict__ w1T,
                         float* __restrict__ w2T2, float* __restrict__ w3T) {
    int idx = blockIdx.x * 256 + threadIdx.x;            // 14336
    if (idx < 8192) {                                    // w_o1 [64][128] -> w1T[j][ho]
        int j = idx >> 6, ho = idx & 63;
        w1T[idx] = w1[ho * 128 + j];
    } else if (idx < 8192 + 2048) {                      // w_o2 [32][64] -> w2T2[j][ho]
        int t = idx - 8192;
        int j = t >> 5, ho = t & 31;
        w2T2[t] = w2[ho * 64 + j];
    } else if (idx < 8192 + 2048 + 4096) {               // w_o3 [128][32] -> w3T[j][jo]
        int t = idx - 8192 - 2048;
        int j = t >> 7, jo = t & 127;
        w3T[t] = w3[jo * 32 + j];
    }
}

__global__ void k_xstats(const float* __restrict__ x, double* __restrict__ xstat) {
    __shared__ float ls[256], lq[256];
    float s = 0, q = 0;
    for (int i = blockIdx.x * 256 + threadIdx.x; i < EE; i += gridDim.x * 256) {
        float v = x[i]; s += v; q += v * v;
    }
    ls[threadIdx.x] = s; lq[threadIdx.x] = q; __syncthreads();
    for (int off = 128; off > 0; off >>= 1) {
        if (threadIdx.x < off) { ls[threadIdx.x] += ls[threadIdx.x + off]; lq[threadIdx.x] += lq[threadIdx.x + off]; }
        __syncthreads();
    }
    if (threadIdx.x == 0) { atomicAdd(&xstat[0], (double)ls[0]); atomicAdd(&xstat[1], (double)lq[0]); }
}

// fused: dst histogram (CSR sort) + x-bin statistics via NATIVE INT atomics
// (f32 atomicAdd compiles to a CAS loop without unsafe-fp-atomics -> R7's 1086us regression)
__global__ void k_hist(const int* __restrict__ dstv, const float* __restrict__ x,
                       int* __restrict__ hist, u32* __restrict__ bc,
                       u64* __restrict__ bs, u64* __restrict__ bq) {
    int e = blockIdx.x * 256 + threadIdx.x;
    if (e >= EE) return;
    atomicAdd(&hist[dstv[e]], 1);
    float tp = fminf(fmaxf((x[e] - XLO) * XSC, 0.f), TPMAX);
    int i = (int)tp; float f = tp - (float)i;
    atomicAdd(&bc[i], 1u);
    atomicAdd(&bs[i], (u64)(u32)(f * 65536.f + 0.5f));
    atomicAdd(&bq[i], (u64)(u32)(f * f * 65536.f + 0.5f));
}

__global__ void k_scanA(const int* __restrict__ hist, int* __restrict__ psum) {
    __shared__ int ls[256];
    int t = threadIdx.x, idx = blockIdx.x * CHUNK + t;
    ls[t] = (t < CHUNK && idx < NN) ? hist[idx] : 0; __syncthreads();
    for (int off = 128; off > 0; off >>= 1) {
        if (t < off) ls[t] += ls[t + off];
        __syncthreads();
    }
    if (t == 0) psum[blockIdx.x] = ls[0];
}

__global__ void k_scanB(const int* __restrict__ psum, int* __restrict__ pbase, int* __restrict__ row_ptr) {
    __shared__ int ls[256];
    int t = threadIdx.x, v = psum[t];
    ls[t] = v; __syncthreads();
    for (int off = 1; off < 256; off <<= 1) {
        int a = ls[t]; int b = (t >= off) ? ls[t - off] : 0; __syncthreads();
        ls[t] = a + b; __syncthreads();
    }
    pbase[t] = ls[t] - v;
    if (t == 0) row_ptr[NN] = EE;
}

__global__ void k_scanC(const int* __restrict__ hist, const int* __restrict__ pbase, int* __restrict__ row_ptr) {
    __shared__ int ls[256];
    int t = threadIdx.x, idx = blockIdx.x * CHUNK + t;
    int v = (t < CHUNK && idx < NN) ? hist[idx] : 0;
    ls[t] = v; __syncthreads();
    for (int off = 1; off < 256; off <<= 1) {
        int a = ls[t]; int b = (t >= off) ? ls[t - off] : 0; __syncthreads();
        ls[t] = a + b; __syncthreads();
    }
    if (t < CHUNK && idx < NN) row_ptr[idx] = pbase[blockIdx.x] + ls[t] - v;
}

__global__ void k_prep2(const double* __restrict__ xstat, const float* __restrict__ w1,
                        const float* __restrict__ g1, const float* __restrict__ be1,
                        float* __restrict__ Aw, float* __restrict__ Cw, float* __restrict__ mxp) {
    int f = threadIdx.x;  // 64
    double mx = xstat[0] / (double)EE;
    double vx = xstat[1] / (double)EE - mx * mx; if (vx < 0) vx = 0;
    float w = w1[f];
    Aw[f] = w * rsqrtf((float)vx * w * w + BN_EPS) * g1[f];
    Cw[f] = be1[f];
    if (f == 0) mxp[0] = (float)mx;
}

// build y(x) table: wave-per-knot, lane = output feature; d1 via shuffle broadcast
__global__ void __launch_bounds__(256) k_ytab(
        const float* __restrict__ Aw, const float* __restrict__ Cw, const float* __restrict__ mxp,
        const float* __restrict__ w2T, const float* __restrict__ b2f, float* __restrict__ ytab) {
    int lane = threadIdx.x & 63;
    int idx = blockIdx.x * 4 + (threadIdx.x >> 6);       // knot id
    if (idx > NTB) return;
    float xi = XLO + (float)idx * DXT;
    float t = xi - mxp[0];
    float d1L = sp(fmaf(Aw[lane], t, Cw[lane]));         // lane holds d1[lane]
    float y = b2f[lane];
    #pragma unroll
    for (int hin = 0; hin < 64; hin++) {
        float d1 = __shfl(d1L, hin, 64);
        y = fmaf(d1, w2T[hin * 64 + lane], y);
    }
    ytab[(size_t)idx * 64 + lane] = y;
}

// BN2 moments from bin statistics (c, s=sum f, q=sum f^2), exact for interpolated y:
// Sum(y) = (c-s)A + sB ; Sum(y^2) = (c-2s+q)A^2 + 2(s-q)AB + qB^2   per bin.
__global__ void __launch_bounds__(256) k_moments(
        const float* __restrict__ ytab, const u32* __restrict__ bc,
        const u64* __restrict__ bs, const u64* __restrict__ bq,
        double* __restrict__ sty) {
    int lane = threadIdx.x & 63;
    int gw = blockIdx.x * 4 + (threadIdx.x >> 6);        // 256 waves total (64 blocks)
    float m1 = 0, m2 = 0;
    int i0 = gw * (NTB / 256);
    for (int i = i0; i < i0 + NTB / 256; ++i) {
        float c = (float)bc[i];
        float s = (float)bs[i] * (1.f / 65536.f);
        float q = (float)bq[i] * (1.f / 65536.f);
        float A = ytab[(size_t)i * 64 + lane];
        float B = ytab[(size_t)(i + 1) * 64 + lane];
        m1 += (c - s) * A + s * B;
        m2 += (c - 2.f * s + q) * A * A + 2.f * (s - q) * A * B + q * B * B;
    }
    __shared__ float lsS[256], lsQ[256];
    lsS[threadIdx.x] = m1; lsQ[threadIdx.x] = m2; __syncthreads();
    if (threadIdx.x < 128) {
        int ff = threadIdx.x & 63; bool isq = threadIdx.x >= 64;
        float acc = 0;
        #pragma unroll
        for (int j = 0; j < 4; j++) acc += isq ? lsQ[j * 64 + ff] : lsS[j * 64 + ff];
        atomicAdd(&sty[threadIdx.x], (double)acc);
    }
}

__global__ void k_ysc(const double* __restrict__ sty, const float* __restrict__ g2,
                      const float* __restrict__ be2, float* __restrict__ sc2, float* __restrict__ sh2) {
    int f = threadIdx.x;  // 64
    double m = sty[f] / (double)EE;
    double var = sty[64 + f] / (double)EE - m * m; if (var < 0) var = 0;
    float rstd = rsqrtf((float)var + BN_EPS);
    float sc = rstd * g2[f];
    sc2[f] = sc;
    sh2[f] = be2[f] - (float)m * sc;
}

// pack affined bf16 pair table: ptab[i][f] = {aff(ytab[i][f]), aff(ytab[i+1][f])}
__global__ void k_ypack(const float* __restrict__ ytab, const float* __restrict__ sc2,
                        const float* __restrict__ sh2, u32* __restrict__ ptab) {
    int tid = blockIdx.x * 256 + threadIdx.x;            // NTB*64
    int f = tid & 63;
    float sc = sc2[f], sh = sh2[f];
    float a = fmaf(ytab[tid], sc, sh);
    float b = fmaf(ytab[tid + 64], sc, sh);
    ptab[tid] = pk2(a, b);
}

// counting-sort edges: write packed {src, et, x} into dst-sorted position
__global__ void __launch_bounds__(256) k_scatter(
        const float* __restrict__ x, const int* __restrict__ src, const int* __restrict__ dstv,
        const int* __restrict__ etv, const int* __restrict__ row_ptr, int* __restrict__ cursor,
        int4* __restrict__ esd) {
    int e = blockIdx.x * 256 + threadIdx.x;
    if (e >= EE) return;
    int d = dstv[e];
    int p = row_ptr[d] + atomicAdd(&cursor[d], 1);
    int4 v; v.x = src[e]; v.y = etv[e]; v.z = __float_as_int(x[e]); v.w = 0;
    esd[p] = v;
}

__device__ __forceinline__ float edge_term(int4 ed, int lane, const u32* __restrict__ ptab,
                                           const float* __restrict__ emb) {
    float xv = __int_as_float(ed.z);
    float tp = fminf(fmaxf((xv - XLO) * XSC, 0.f), TPMAX);
    int i = (int)tp; float f = tp - (float)i;
    u32 pr = ptab[i * 64 + lane];
    float a = bf2f((u16)(pr & 0xffff)), b = bf2f((u16)(pr >> 16));
    float y = fmaf(f, b - a, a);                         // BN2-affined y
    return y * emb[(size_t)ed.y * 64 + lane];
}

// wave-per-node aggregation, lane = feature; generic h input; unroll-4
__global__ void __launch_bounds__(256) k_agg(
        const float* __restrict__ h, const int4* __restrict__ esd, const int* __restrict__ row_ptr,
        const u32* __restrict__ ptab, const float* __restrict__ emb, float* __restrict__ hpre) {
    int lane = threadIdx.x & 63;
    int n = __builtin_amdgcn_readfirstlane((int)(blockIdx.x * 4 + (threadIdx.x >> 6)));
    if (n >= NN) return;
    int p0 = row_ptr[n], p1 = row_ptr[n + 1];
    float acc = 0.f;
    int p = p0;
    for (; p + 4 <= p1; p += 4) {
        int4 e0 = esd[p], e1 = esd[p + 1], e2 = esd[p + 2], e3 = esd[p + 3];
        float h0 = h[(size_t)e0.x * 64 + lane];
        float h1 = h[(size_t)e1.x * 64 + lane];
        float h2 = h[(size_t)e2.x * 64 + lane];
        float h3 = h[(size_t)e3.x * 64 + lane];
        float a0 = edge_term(e0, lane, ptab, emb);
        float a1 = edge_term(e1, lane, ptab, emb);
        float a2 = edge_term(e2, lane, ptab, emb);
        float a3 = edge_term(e3, lane, ptab, emb);
        acc += sp(h0 + a0) + sp(h1 + a1) + sp(h2 + a2) + sp(h3 + a3);
    }
    for (; p < p1; ++p) {
        int4 e0 = esd[p];
        float h0 = h[(size_t)e0.x * 64 + lane];
        acc += sp(h0 + edge_term(e0, lane, ptab, emb));
    }
    size_t o = (size_t)n * 64 + lane;
    hpre[o] = acc + h[o];
}

// gconv1 variant: h comes from node_emb[node_type] (L1-resident)
__global__ void __launch_bounds__(256) k_agg0(
        const int* __restrict__ nt, const float* __restrict__ nemb, const int4* __restrict__ esd,
        const int* __restrict__ row_ptr, const u32* __restrict__ ptab,
        const float* __restrict__ emb, float* __restrict__ hpre) {
    int lane = threadIdx.x & 63;
    int n = __builtin_amdgcn_readfirstlane((int)(blockIdx.x * 4 + (threadIdx.x >> 6)));
    if (n >= NN) return;
    int p0 = row_ptr[n], p1 = row_ptr[n + 1];
    float acc = 0.f;
    int p = p0;
    for (; p + 4 <= p1; p += 4) {
        int4 e0 = esd[p], e1 = esd[p + 1], e2 = esd[p + 2], e3 = esd[p + 3];
        float h0 = nemb[(size_t)nt[e0.x] * 64 + lane];
        float h1 = nemb[(size_t)nt[e1.x] * 64 + lane];
        float h2 = nemb[(size_t)nt[e2.x] * 64 + lane];
        float h3 = nemb[(size_t)nt[e3.x] * 64 + lane];
        float a0 = edge_term(e0, lane, ptab, emb);
        float a1 = edge_term(e1, lane, ptab, emb);
        float a2 = edge_term(e2, lane, ptab, emb);
        float a3 = edge_term(e3, lane, ptab, emb);
        acc += sp(h0 + a0) + sp(h1 + a1) + sp(h2 + a2) + sp(h3 + a3);
    }
    for (; p < p1; ++p) {
        int4 e0 = esd[p];
        float h0 = nemb[(size_t)nt[e0.x] * 64 + lane];
        acc += sp(h0 + edge_term(e0, lane, ptab, emb));
    }
    hpre[(size_t)n * 64 + lane] = acc + nemb[(size_t)nt[n] * 64 + lane];
}

// per-feature mean/var partials over [rows, C] (C = 1<<logC), f64 atomics
__global__ void k_fstats(const float* __restrict__ v, int rows, int logC, double* __restrict__ stat) {
    int C = 1 << logC;
    int f = threadIdx.x & (C - 1);
    int r0 = threadIdx.x >> logC;
    int rpb = 256 >> logC;
    float s = 0, q = 0;
    for (int r = blockIdx.x * rpb + r0; r < rows; r += gridDim.x * rpb) {
        float val = v[(size_t)r * C + f];
        s += val; q += val * val;
    }
    __shared__ float lsS[256], lsQ[256];
    lsS[threadIdx.x] = s; lsQ[threadIdx.x] = q; __syncthreads();
    if (threadIdx.x < C) {
        float ss = 0, qq = 0;
        for (int j = 0; j < rpb; j++) { ss += lsS[j * C + threadIdx.x]; qq += lsQ[j * C + threadIdx.x]; }
        atomicAdd(&stat[threadIdx.x], (double)ss);
        atomicAdd(&stat[C + threadIdx.x], (double)qq);
    }
}

__global__ void k_bn(const float* __restrict__ in, float* __restrict__ out,
                     const double* __restrict__ stat, const float* __restrict__ g,
                     const float* __restrict__ be, int rows, int logC, int act) {
    int C = 1 << logC;
    size_t total = (size_t)rows << logC;
    size_t i = (size_t)blockIdx.x * 256 + threadIdx.x;
    if (i >= total) return;
    int f = (int)(i & (C - 1));
    double m = stat[f] / (double)rows;
    double var = stat[C + f] / (double)rows - m * m; if (var < 0) var = 0;
    float rstd = rsqrtf((float)var + BN_EPS);
    float val = (in[i] - (float)m) * rstd * g[f] + be[f];
    out[i] = act ? sp(val) : val;
}

__global__ void k_hglobal(const float* __restrict__ h, const int* __restrict__ batch, float* __restrict__ hg) {
    int idx = blockIdx.x * 256 + threadIdx.x;            // N*64
    int n = idx >> 6, f = idx & 63;
    atomicAdd(&hg[(size_t)batch[n] * 64 + f], h[idx]);
}

// head GEMV 1: lane = output feature; coalesced w1T rows; input broadcast via shfl
__global__ void __launch_bounds__(256) k_o1(
        const float* __restrict__ h, const float* __restrict__ hg, const int* __restrict__ batch,
        const float* __restrict__ w1T, const float* __restrict__ b1, float* __restrict__ z1) {
    int lane = threadIdx.x & 63;
    int n = __builtin_amdgcn_readfirstlane((int)(blockIdx.x * 4 + (threadIdx.x >> 6)));
    if (n >= NN) return;
    int b = batch[n];
    float hl = h[(size_t)n * 64 + lane];
    float gl = hg[(size_t)b * 64 + lane];
    float acc = b1[lane];
    #pragma unroll
    for (int j = 0; j < 64; j++)
        acc = fmaf(__shfl(hl, j, 64), w1T[j * 64 + lane], acc);
    #pragma unroll
    for (int j = 0; j < 64; j++)
        acc = fmaf(__shfl(gl, j, 64), w1T[(64 + j) * 64 + lane], acc);
    z1[(size_t)n * 64 + lane] = acc;
}

// head GEMV 2: 2 nodes per wave, lane = (node half, output feature 0..31)
__global__ void __launch_bounds__(256) k_o2(
        const float* __restrict__ o1v, const float* __restrict__ w2T2,
        const float* __restrict__ b2, float* __restrict__ z2) {
    int tid = threadIdx.x;
    int lane = tid & 63;
    int ho = lane & 31;
    int base = lane & 32;                                // my half's lane base
    int n = blockIdx.x * 8 + (tid >> 5);
    if (n >= NN) return;
    float hl = o1v[(size_t)n * 64 + ho];
    float hh = o1v[(size_t)n * 64 + 32 + ho];
    float acc = b2[ho];
    #pragma unroll
    for (int j = 0; j < 32; j++)
        acc = fmaf(__shfl(hl, base + j, 64), w2T2[j * 32 + ho], acc);
    #pragma unroll
    for (int j = 0; j < 32; j++)
        acc = fmaf(__shfl(hh, base + j, 64), w2T2[(32 + j) * 32 + ho], acc);
    z2[(size_t)n * 32 + ho] = acc;
}

// head GEMV 3: 2 waves per node (jo = 0..127), coalesced w3T rows
__global__ void __launch_bounds__(256) k_o3(
        const float* __restrict__ o2v, const float* __restrict__ w3T,
        const float* __restrict__ b3, float* __restrict__ outp) {
    int gtid = blockIdx.x * 256 + threadIdx.x;           // N*128
    int lane = threadIdx.x & 63;
    int w = gtid >> 6;
    int n = w >> 1;
    int jo = ((w & 1) << 6) + lane;
    if (n >= NN) return;
    float zl = o2v[(size_t)n * 32 + (lane & 31)];
    float acc = b3[jo];
    #pragma unroll
    for (int j = 0; j < 32; j++)
        acc = fmaf(__shfl(zl, j, 64), w3T[j * 128 + jo], acc);
    size_t dsti = (jo < 64) ? ((size_t)n * 64 + jo) : ((size_t)NN * 64 + (size_t)n * 64 + (jo - 64));
    outp[dsti] = acc;                                    // f32 output
}

extern "C" void kernel_launch(void* const* d_in, const int* in_sizes, int n_in,
                              void* d_out, int out_size, void* d_ws, size_t ws_size,
                              hipStream_t stream) {
    const float* x        = (const float*)d_in[0];
    const int* node_type  = (const int*)d_in[1];
    const int* edge_type  = (const int*)d_in[2];
    const int* edge_index = (const int*)d_in[3];
    const int* batch      = (const int*)d_in[4];
    const float* node_emb = (const float*)d_in[5];
    const float* edge_emb = (const float*)d_in[6];
    const float* w_d1 = (const float*)d_in[7];  const float* b_d1 = (const float*)d_in[8];
    const float* g_d1 = (const float*)d_in[9];  const float* be_d1 = (const float*)d_in[10];
    const float* w_d2 = (const float*)d_in[11]; const float* b_d2 = (const float*)d_in[12];
    const float* g_d2 = (const float*)d_in[13]; const float* be_d2 = (const float*)d_in[14];
    const float* g_c1 = (const float*)d_in[15]; const float* be_c1 = (const float*)d_in[16];
    const float* g_c2 = (const float*)d_in[17]; const float* be_c2 = (const float*)d_in[18];
    const float* g_c3 = (const float*)d_in[19]; const float* be_c3 = (const float*)d_in[20];
    const float* w_o1 = (const float*)d_in[21]; const float* b_o1 = (const float*)d_in[22];
    const float* g_o1 = (const float*)d_in[23]; const float* be_o1 = (const float*)d_in[24];
    const float* w_o2 = (const float*)d_in[25]; const float* b_o2 = (const float*)d_in[26];
    const float* g_o2 = (const float*)d_in[27]; const float* be_o2 = (const float*)d_in[28];
    const float* w_o3 = (const float*)d_in[29]; const float* b_o3 = (const float*)d_in[30];
    (void)b_d1;  // cancels inside BN1 (mean subtraction removes per-feature shift)
    const int* src  = edge_index;
    const int* dstv = edge_index + EE;

    char* ws = (char*)d_ws;
    int4*  esd     = (int4*)(ws + OFF_ESD);
    int*   row_ptr = (int*)(ws + OFF_ROWP);
    float* hA   = (float*)(ws + OFF_HA);
    float* hB   = (float*)(ws + OFF_HB);
    float* zb   = (float*)(ws + OFF_ZB);
    float* ytab = (float*)(ws + OFF_YTAB);
    u32*   ptab = (u32*)(ws + OFF_PTAB);
    float* w2T  = (float*)(ws + OFF_W2T);
    float* b2f  = (float*)(ws + OFF_B2F);
    float* Aw   = (float*)(ws + OFF_AW);
    float* Cw   = (float*)(ws + OFF_CW);
    float* mxp  = (float*)(ws + OFF_MX);
    float* sc2  = (float*)(ws + OFF_SC2);
    float* sh2  = (float*)(ws + OFF_SH2);
    int*   psum = (int*)(ws + OFF_PSUM);
    int*   pbase= (int*)(ws + OFF_PBASE);
    float* w1T  = (float*)(ws + OFF_W1T);
    float* w2T2 = (float*)(ws + OFF_W2O);
    float* w3T  = (float*)(ws + OFF_W3T);
    int*   hist   = (int*)(ws + OFF_HIST);
    int*   cursor = (int*)(ws + OFF_CUR);
    float* hg     = (float*)(ws + OFF_HG);
    double* xstat = (double*)(ws + OFF_XSTAT);
    double* sty   = (double*)(ws + OFF_STY);
    double* fst   = (double*)(ws + OFF_FST);
    u32*   bc = (u32*)(ws + OFF_BC);
    u64*   bs = (u64*)(ws + OFF_BS);
    u64*   bq = (u64*)(ws + OFF_BQ);
    double* st0 = fst;          double* st1 = fst + 128;  double* st2 = fst + 256;
    double* st3 = fst + 384;    double* st4 = fst + 512;

    hipMemsetAsync(ws + OFF_HIST, 0, ZERO_BYTES, stream);

    k_w2prep<<<16, 256, 0, stream>>>(w_d2, b_d2, w2T, b2f);
    k_otprep<<<56, 256, 0, stream>>>(w_o1, w_o2, w_o3, w1T, w2T2, w3T);
    k_xstats<<<512, 256, 0, stream>>>(x, xstat);
    k_hist<<<NBY, 256, 0, stream>>>(dstv, x, hist, bc, bs, bq);
    k_scanA<<<256, 256, 0, stream>>>(hist, psum);
    k_scanB<<<1, 256, 0, stream>>>(psum, pbase, row_ptr);
    k_scanC<<<256, 256, 0, stream>>>(hist, pbase, row_ptr);
    k_prep2<<<1, 64, 0, stream>>>(xstat, w_d1, g_d1, be_d1, Aw, Cw, mxp);
    k_ytab<<<(NTB + 1 + 3) / 4, 256, 0, stream>>>(Aw, Cw, mxp, w2T, b2f, ytab);
    k_scatter<<<NBY, 256, 0, stream>>>(x, src, dstv, edge_type, row_ptr, cursor, esd);
    k_moments<<<64, 256, 0, stream>>>(ytab, bc, bs, bq, sty);
    k_ysc<<<1, 64, 0, stream>>>(sty, g_d2, be_d2, sc2, sh2);
    k_ypack<<<NTB * 64 / 256, 256, 0, stream>>>(ytab, sc2, sh2, ptab);
    // gconv 1 (h from node_emb[node_type], L1-resident)
    k_agg0<<<12500, 256, 0, stream>>>(node_type, node_emb, esd, row_ptr, ptab, edge_emb, hB);
    k_fstats<<<1024, 256, 0, stream>>>(hB, NN, 6, st0);
    k_bn<<<12500, 256, 0, stream>>>(hB, hB, st0, g_c1, be_c1, NN, 6, 1);
    // gconv 2
    k_agg<<<12500, 256, 0, stream>>>(hB, esd, row_ptr, ptab, edge_emb, hA);
    k_fstats<<<1024, 256, 0, stream>>>(hA, NN, 6, st1);
    k_bn<<<12500, 256, 0, stream>>>(hA, hA, st1, g_c2, be_c2, NN, 6, 1);
    // gconv 3 (no activation)
    k_agg<<<12500, 256, 0, stream>>>(hA, esd, row_ptr, ptab, edge_emb, hB);
    k_fstats<<<1024, 256, 0, stream>>>(hB, NN, 6, st2);
    k_bn<<<12500, 256, 0, stream>>>(hB, hB, st2, g_c3, be_c3, NN, 6, 0);
    // global pool + head
    k_hglobal<<<12500, 256, 0, stream>>>(hB, batch, hg);
    k_o1<<<12500, 256, 0, stream>>>(hB, hg, batch, w1T, b_o1, hA);
    k_fstats<<<1024, 256, 0, stream>>>(hA, NN, 6, st3);
    k_bn<<<12500, 256, 0, stream>>>(hA, hA, st3, g_o1, be_o1, NN, 6, 1);
    k_o2<<<6250, 256, 0, stream>>>(hA, w2T2, b_o2, zb);
    k_fstats<<<1024, 256, 0, stream>>>(zb, NN, 5, st4);
    k_bn<<<6250, 256, 0, stream>>>(zb, zb, st4, g_o2, be_o2, NN, 5, 1);
    k_o3<<<25000, 256, 0, stream>>>(zb, w3T, b_o3, (float*)d_out);
    (void)in_sizes; (void)n_in; (void)out_size; (void)ws_size;
}

// Round 9
// 934.872 us; speedup vs baseline: 2.0729x; 1.3463x over previous
//
#include <hip/hip_runtime.h>
#include <stdint.h>

#define NN 50000
#define EE 1250000
#define BB 500
#define NBY 4883      // ceil(EE/256)
#define CHUNK 196     // ceil(NN/256) for scan partitions
#define BN_EPS 1e-5f

#define NTB 8192      // table intervals; 8193 knots
#define XLO (-12.0f)
#define XHI (12.0f)
#define XSC ((float)NTB / (XHI - XLO))   // knots at XLO + i/XSC
#define DXT ((XHI - XLO) / (float)NTB)
#define TPMAX 8191.999f

using u16 = unsigned short;
using u32 = unsigned int;

__device__ __forceinline__ float bf2f(u16 v) { return __uint_as_float(((u32)v) << 16); }
__device__ __forceinline__ u16 f2bf(float f) {
    u32 u = __float_as_uint(f);
    return (u16)((u + 0x7fffu + ((u >> 16) & 1u)) >> 16);
}
__device__ __forceinline__ u32 pk2(float a, float b) { return (u32)f2bf(a) | ((u32)f2bf(b) << 16); }
__device__ __forceinline__ float sp(float z) {   // softplus = max(z,0)+log1p(exp(-|z|))
    float t = __expf(-fabsf(z));
    return fmaxf(z, 0.f) + __logf(1.f + t);
}

// ---------------- workspace layout (~65 MB) ----------------
constexpr size_t OFF_ESD  = 0;                                    // int4 [E] {src, et, x_bits, 0}
constexpr size_t OFF_ROWP = OFF_ESD + (size_t)EE * 16;            // row_ptr [N+1]
constexpr size_t OFF_HA   = (OFF_ROWP + (size_t)(NN + 1) * 4 + 255) & ~(size_t)255;
constexpr size_t OFF_HB   = OFF_HA + (size_t)NN * 64 * 4;
constexpr size_t OFF_ZB   = OFF_HB + (size_t)NN * 64 * 4;         // [N,32]
constexpr size_t OFF_YTAB = OFF_ZB + (size_t)NN * 32 * 4;         // f32 [NTB+1][64]
constexpr size_t OFF_PTAB = OFF_YTAB + (size_t)(NTB + 1) * 64 * 4;// u32 [NTB][64] bf16 pairs (affined)
constexpr size_t OFF_W2T  = OFF_PTAB + (size_t)NTB * 64 * 4;      // w_d2 transposed f32 [64][64]
constexpr size_t OFF_B2F  = OFF_W2T + 4096 * 4;
constexpr size_t OFF_AW   = OFF_B2F + 256;
constexpr size_t OFF_CW   = OFF_AW + 256;
constexpr size_t OFF_MX   = OFF_CW + 256;
constexpr size_t OFF_SC2  = OFF_MX + 256;
constexpr size_t OFF_SH2  = OFF_SC2 + 256;
constexpr size_t OFF_PSUM = OFF_SH2 + 256;                        // [256] int
constexpr size_t OFF_PBASE= OFF_PSUM + 1024;                      // [256] int
constexpr size_t OFF_W1T  = OFF_PBASE + 1024;                     // f32 [128][64] (w_o1^T)
constexpr size_t OFF_W2O  = OFF_W1T + 8192 * 4;                   // f32 [64][32]  (w_o2^T)
constexpr size_t OFF_W3T  = OFF_W2O + 2048 * 4;                   // f32 [32][128] (w_o3^T)
// zero region (one memset): hist | cursor | hg | xstat | sty | 5 stat slots
constexpr size_t OFF_HIST = (OFF_W3T + 4096 * 4 + 255) & ~(size_t)255;
constexpr size_t OFF_CUR  = OFF_HIST + (size_t)NN * 4;
constexpr size_t OFF_HG   = OFF_CUR + (size_t)NN * 4;
constexpr size_t OFF_XSTAT= OFF_HG + (size_t)BB * 64 * 4;         // 2 doubles
constexpr size_t OFF_STY  = OFF_XSTAT + 16;                       // 128 doubles
constexpr size_t OFF_FST  = OFF_STY + 128 * 8;
constexpr size_t ZERO_END = OFF_FST + 5 * 128 * 8;
constexpr size_t ZERO_BYTES = ZERO_END - OFF_HIST;

// ---------------- prep kernels ----------------
__global__ void k_w2prep(const float* __restrict__ w2, const float* __restrict__ b2,
                         float* __restrict__ w2T, float* __restrict__ b2f) {
    int idx = blockIdx.x * 256 + threadIdx.x;            // 4096
    int hin = idx >> 6, ho = idx & 63;
    w2T[idx] = w2[ho * 64 + hin];                        // w2T[hin][ho] = w_d2[ho][hin]
    if (idx < 64) b2f[idx] = b2[idx];
}

// transpose head weights for coalesced lane=outfeature GEMVs
__global__ void k_otprep(const float* __restrict__ w1, const float* __restrict__ w2,
                         const float* __restrict__ w3, float* __restrict__ w1T,
                         float* __restrict__ w2T2, float* __restrict__ w3T) {
    int idx = blockIdx.x * 256 + threadIdx.x;            // 14336
    if (idx < 8192) {                                    // w_o1 [64][128] -> w1T[j][ho]
        int j = idx >> 6, ho = idx & 63;
        w1T[idx] = w1[ho * 128 + j];
    } else if (idx < 8192 + 2048) {                      // w_o2 [32][64] -> w2T2[j][ho]
        int t = idx - 8192;
        int j = t >> 5, ho = t & 31;
        w2T2[t] = w2[ho * 64 + j];
    } else if (idx < 8192 + 2048 + 4096) {               // w_o3 [128][32] -> w3T[j][jo]
        int t = idx - 8192 - 2048;
        int j = t >> 7, jo = t & 127;
        w3T[t] = w3[jo * 32 + j];
    }
}

__global__ void k_xstats(const float* __restrict__ x, double* __restrict__ xstat) {
    __shared__ float ls[256], lq[256];
    float s = 0, q = 0;
    for (int i = blockIdx.x * 256 + threadIdx.x; i < EE; i += gridDim.x * 256) {
        float v = x[i]; s += v; q += v * v;
    }
    ls[threadIdx.x] = s; lq[threadIdx.x] = q; __syncthreads();
    for (int off = 128; off > 0; off >>= 1) {
        if (threadIdx.x < off) { ls[threadIdx.x] += ls[threadIdx.x + off]; lq[threadIdx.x] += lq[threadIdx.x + off]; }
        __syncthreads();
    }
    if (threadIdx.x == 0) { atomicAdd(&xstat[0], (double)ls[0]); atomicAdd(&xstat[1], (double)lq[0]); }
}

// dst histogram only (R7/R8 bin atomics were memory-side-RMW bound: 3.75M contended
// device-scope atomics -> 437us; BN2 stats now come from the dense table scan k_ymom)
__global__ void k_hist(const int* __restrict__ dstv, int* __restrict__ hist) {
    int e = blockIdx.x * 256 + threadIdx.x;
    if (e < EE) atomicAdd(&hist[dstv[e]], 1);
}

__global__ void k_scanA(const int* __restrict__ hist, int* __restrict__ psum) {
    __shared__ int ls[256];
    int t = threadIdx.x, idx = blockIdx.x * CHUNK + t;
    ls[t] = (t < CHUNK && idx < NN) ? hist[idx] : 0; __syncthreads();
    for (int off = 128; off > 0; off >>= 1) {
        if (t < off) ls[t] += ls[t + off];
        __syncthreads();
    }
    if (t == 0) psum[blockIdx.x] = ls[0];
}

__global__ void k_scanB(const int* __restrict__ psum, int* __restrict__ pbase, int* __restrict__ row_ptr) {
    __shared__ int ls[256];
    int t = threadIdx.x, v = psum[t];
    ls[t] = v; __syncthreads();
    for (int off = 1; off < 256; off <<= 1) {
        int a = ls[t]; int b = (t >= off) ? ls[t - off] : 0; __syncthreads();
        ls[t] = a + b; __syncthreads();
    }
    pbase[t] = ls[t] - v;
    if (t == 0) row_ptr[NN] = EE;
}

__global__ void k_scanC(const int* __restrict__ hist, const int* __restrict__ pbase, int* __restrict__ row_ptr) {
    __shared__ int ls[256];
    int t = threadIdx.x, idx = blockIdx.x * CHUNK + t;
    int v = (t < CHUNK && idx < NN) ? hist[idx] : 0;
    ls[t] = v; __syncthreads();
    for (int off = 1; off < 256; off <<= 1) {
        int a = ls[t]; int b = (t >= off) ? ls[t - off] : 0; __syncthreads();
        ls[t] = a + b; __syncthreads();
    }
    if (t < CHUNK && idx < NN) row_ptr[idx] = pbase[blockIdx.x] + ls[t] - v;
}

__global__ void k_prep2(const double* __restrict__ xstat, const float* __restrict__ w1,
                        const float* __restrict__ g1, const float* __restrict__ be1,
                        float* __restrict__ Aw, float* __restrict__ Cw, float* __restrict__ mxp) {
    int f = threadIdx.x;  // 64
    double mx = xstat[0] / (double)EE;
    double vx = xstat[1] / (double)EE - mx * mx; if (vx < 0) vx = 0;
    float w = w1[f];
    Aw[f] = w * rsqrtf((float)vx * w * w + BN_EPS) * g1[f];
    Cw[f] = be1[f];
    if (f == 0) mxp[0] = (float)mx;
}

// build y(x) table: wave-per-knot, lane = output feature; d1 via shuffle broadcast
__global__ void __launch_bounds__(256) k_ytab(
        const float* __restrict__ Aw, const float* __restrict__ Cw, const float* __restrict__ mxp,
        const float* __restrict__ w2T, const float* __restrict__ b2f, float* __restrict__ ytab) {
    int lane = threadIdx.x & 63;
    int idx = blockIdx.x * 4 + (threadIdx.x >> 6);       // knot id
    if (idx > NTB) return;
    float xi = XLO + (float)idx * DXT;
    float t = xi - mxp[0];
    float d1L = sp(fmaf(Aw[lane], t, Cw[lane]));         // lane holds d1[lane]
    float y = b2f[lane];
    #pragma unroll
    for (int hin = 0; hin < 64; hin++) {
        float d1 = __shfl(d1L, hin, 64);
        y = fmaf(d1, w2T[hin * 64 + lane], y);
    }
    ytab[(size_t)idx * 64 + lane] = y;
}

// BN2 moments: dense scan of all E edges through the f32 table, lane = feature.
// R6 version was a serial dependent chain (4096 waves x 305 edges, 1 edge in flight).
// Now: 4883 waves x 256 edges, UNROLL-4 (8 independent 256B ytab row loads in flight).
__device__ __forceinline__ void ymom_edge(float xv, const float* __restrict__ ytab, int lane,
                                          float& s, float& q) {
    float tp = fminf(fmaxf((xv - XLO) * XSC, 0.f), TPMAX);
    int i = (int)tp; float f = tp - (float)i;
    float a = ytab[(size_t)i * 64 + lane];
    float b = ytab[(size_t)(i + 1) * 64 + lane];
    float y = fmaf(f, b - a, a);
    s += y; q += y * y;
}

__global__ void __launch_bounds__(256) k_ymom(
        const float* __restrict__ x, const float* __restrict__ ytab, double* __restrict__ sty) {
    int lane = threadIdx.x & 63;
    int wid = (blockIdx.x * 256 + threadIdx.x) >> 6;     // 4884 waves (1221 blocks)
    float s = 0, q = 0;
    int e0 = wid * 256;
    int e1 = e0 + 256; if (e1 > EE) e1 = EE;
    int p = e0;
    for (; p + 4 <= e1; p += 4) {
        float x0 = x[p], x1 = x[p + 1], x2 = x[p + 2], x3 = x[p + 3];
        ymom_edge(x0, ytab, lane, s, q);
        ymom_edge(x1, ytab, lane, s, q);
        ymom_edge(x2, ytab, lane, s, q);
        ymom_edge(x3, ytab, lane, s, q);
    }
    for (; p < e1; ++p) ymom_edge(x[p], ytab, lane, s, q);
    __shared__ float lsS[256], lsQ[256];
    lsS[threadIdx.x] = s; lsQ[threadIdx.x] = q; __syncthreads();
    if (threadIdx.x < 128) {
        int ff = threadIdx.x & 63; bool isq = threadIdx.x >= 64;
        float acc = 0;
        #pragma unroll
        for (int j = 0; j < 4; j++) acc += isq ? lsQ[j * 64 + ff] : lsS[j * 64 + ff];
        atomicAdd(&sty[threadIdx.x], (double)acc);
    }
}

__global__ void k_ysc(const double* __restrict__ sty, const float* __restrict__ g2,
                      const float* __restrict__ be2, float* __restrict__ sc2, float* __restrict__ sh2) {
    int f = threadIdx.x;  // 64
    double m = sty[f] / (double)EE;
    double var = sty[64 + f] / (double)EE - m * m; if (var < 0) var = 0;
    float rstd = rsqrtf((float)var + BN_EPS);
    float sc = rstd * g2[f];
    sc2[f] = sc;
    sh2[f] = be2[f] - (float)m * sc;
}

// pack affined bf16 pair table: ptab[i][f] = {aff(ytab[i][f]), aff(ytab[i+1][f])}
__global__ void k_ypack(const float* __restrict__ ytab, const float* __restrict__ sc2,
                        const float* __restrict__ sh2, u32* __restrict__ ptab) {
    int tid = blockIdx.x * 256 + threadIdx.x;            // NTB*64
    int f = tid & 63;
    float sc = sc2[f], sh = sh2[f];
    float a = fmaf(ytab[tid], sc, sh);
    float b = fmaf(ytab[tid + 64], sc, sh);
    ptab[tid] = pk2(a, b);
}

// counting-sort edges: write packed {src, et, x} into dst-sorted position
__global__ void __launch_bounds__(256) k_scatter(
        const float* __restrict__ x, const int* __restrict__ src, const int* __restrict__ dstv,
        const int* __restrict__ etv, const int* __restrict__ row_ptr, int* __restrict__ cursor,
        int4* __restrict__ esd) {
    int e = blockIdx.x * 256 + threadIdx.x;
    if (e >= EE) return;
    int d = dstv[e];
    int p = row_ptr[d] + atomicAdd(&cursor[d], 1);
    int4 v; v.x = src[e]; v.y = etv[e]; v.z = __float_as_int(x[e]); v.w = 0;
    esd[p] = v;
}

__device__ __forceinline__ float edge_term(int4 ed, int lane, const u32* __restrict__ ptab,
                                           const float* __restrict__ emb) {
    float xv = __int_as_float(ed.z);
    float tp = fminf(fmaxf((xv - XLO) * XSC, 0.f), TPMAX);
    int i = (int)tp; float f = tp - (float)i;
    u32 pr = ptab[i * 64 + lane];
    float a = bf2f((u16)(pr & 0xffff)), b = bf2f((u16)(pr >> 16));
    float y = fmaf(f, b - a, a);                         // BN2-affined y
    return y * emb[(size_t)ed.y * 64 + lane];
}

// wave-per-node aggregation, lane = feature; generic h input; unroll-4
__global__ void __launch_bounds__(256) k_agg(
        const float* __restrict__ h, const int4* __restrict__ esd, const int* __restrict__ row_ptr,
        const u32* __restrict__ ptab, const float* __restrict__ emb, float* __restrict__ hpre) {
    int lane = threadIdx.x & 63;
    int n = __builtin_amdgcn_readfirstlane((int)(blockIdx.x * 4 + (threadIdx.x >> 6)));
    if (n >= NN) return;
    int p0 = row_ptr[n], p1 = row_ptr[n + 1];
    float acc = 0.f;
    int p = p0;
    for (; p + 4 <= p1; p += 4) {
        int4 e0 = esd[p], e1 = esd[p + 1], e2 = esd[p + 2], e3 = esd[p + 3];
        float h0 = h[(size_t)e0.x * 64 + lane];
        float h1 = h[(size_t)e1.x * 64 + lane];
        float h2 = h[(size_t)e2.x * 64 + lane];
        float h3 = h[(size_t)e3.x * 64 + lane];
        float a0 = edge_term(e0, lane, ptab, emb);
        float a1 = edge_term(e1, lane, ptab, emb);
        float a2 = edge_term(e2, lane, ptab, emb);
        float a3 = edge_term(e3, lane, ptab, emb);
        acc += sp(h0 + a0) + sp(h1 + a1) + sp(h2 + a2) + sp(h3 + a3);
    }
    for (; p < p1; ++p) {
        int4 e0 = esd[p];
        float h0 = h[(size_t)e0.x * 64 + lane];
        acc += sp(h0 + edge_term(e0, lane, ptab, emb));
    }
    size_t o = (size_t)n * 64 + lane;
    hpre[o] = acc + h[o];
}

// gconv1 variant: h comes from node_emb[node_type] (L1-resident)
__global__ void __launch_bounds__(256) k_agg0(
        const int* __restrict__ nt, const float* __restrict__ nemb, const int4* __restrict__ esd,
        const int* __restrict__ row_ptr, const u32* __restrict__ ptab,
        const float* __restrict__ emb, float* __restrict__ hpre) {
    int lane = threadIdx.x & 63;
    int n = __builtin_amdgcn_readfirstlane((int)(blockIdx.x * 4 + (threadIdx.x >> 6)));
    if (n >= NN) return;
    int p0 = row_ptr[n], p1 = row_ptr[n + 1];
    float acc = 0.f;
    int p = p0;
    for (; p + 4 <= p1; p += 4) {
        int4 e0 = esd[p], e1 = esd[p + 1], e2 = esd[p + 2], e3 = esd[p + 3];
        float h0 = nemb[(size_t)nt[e0.x] * 64 + lane];
        float h1 = nemb[(size_t)nt[e1.x] * 64 + lane];
        float h2 = nemb[(size_t)nt[e2.x] * 64 + lane];
        float h3 = nemb[(size_t)nt[e3.x] * 64 + lane];
        float a0 = edge_term(e0, lane, ptab, emb);
        float a1 = edge_term(e1, lane, ptab, emb);
        float a2 = edge_term(e2, lane, ptab, emb);
        float a3 = edge_term(e3, lane, ptab, emb);
        acc += sp(h0 + a0) + sp(h1 + a1) + sp(h2 + a2) + sp(h3 + a3);
    }
    for (; p < p1; ++p) {
        int4 e0 = esd[p];
        float h0 = nemb[(size_t)nt[e0.x] * 64 + lane];
        acc += sp(h0 + edge_term(e0, lane, ptab, emb));
    }
    hpre[(size_t)n * 64 + lane] = acc + nemb[(size_t)nt[n] * 64 + lane];
}

// per-feature mean/var partials over [rows, C] (C = 1<<logC), f64 atomics
__global__ void k_fstats(const float* __restrict__ v, int rows, int logC, double* __restrict__ stat) {
    int C = 1 << logC;
    int f = threadIdx.x & (C - 1);
    int r0 = threadIdx.x >> logC;
    int rpb = 256 >> logC;
    float s = 0, q = 0;
    for (int r = blockIdx.x * rpb + r0; r < rows; r += gridDim.x * rpb) {
        float val = v[(size_t)r * C + f];
        s += val; q += val * val;
    }
    __shared__ float lsS[256], lsQ[256];
    lsS[threadIdx.x] = s; lsQ[threadIdx.x] = q; __syncthreads();
    if (threadIdx.x < C) {
        float ss = 0, qq = 0;
        for (int j = 0; j < rpb; j++) { ss += lsS[j * C + threadIdx.x]; qq += lsQ[j * C + threadIdx.x]; }
        atomicAdd(&stat[threadIdx.x], (double)ss);
        atomicAdd(&stat[C + threadIdx.x], (double)qq);
    }
}

__global__ void k_bn(const float* __restrict__ in, float* __restrict__ out,
                     const double* __restrict__ stat, const float* __restrict__ g,
                     const float* __restrict__ be, int rows, int logC, int act) {
    int C = 1 << logC;
    size_t total = (size_t)rows << logC;
    size_t i = (size_t)blockIdx.x * 256 + threadIdx.x;
    if (i >= total) return;
    int f = (int)(i & (C - 1));
    double m = stat[f] / (double)rows;
    double var = stat[C + f] / (double)rows - m * m; if (var < 0) var = 0;
    float rstd = rsqrtf((float)var + BN_EPS);
    float val = (in[i] - (float)m) * rstd * g[f] + be[f];
    out[i] = act ? sp(val) : val;
}

__global__ void k_hglobal(const float* __restrict__ h, const int* __restrict__ batch, float* __restrict__ hg) {
    int idx = blockIdx.x * 256 + threadIdx.x;            // N*64
    int n = idx >> 6, f = idx & 63;
    atomicAdd(&hg[(size_t)batch[n] * 64 + f], h[idx]);
}

// head GEMV 1: lane = output feature; coalesced w1T rows; input broadcast via shfl
__global__ void __launch_bounds__(256) k_o1(
        const float* __restrict__ h, const float* __restrict__ hg, const int* __restrict__ batch,
        const float* __restrict__ w1T, const float* __restrict__ b1, float* __restrict__ z1) {
    int lane = threadIdx.x & 63;
    int n = __builtin_amdgcn_readfirstlane((int)(blockIdx.x * 4 + (threadIdx.x >> 6)));
    if (n >= NN) return;
    int b = batch[n];
    float hl = h[(size_t)n * 64 + lane];
    float gl = hg[(size_t)b * 64 + lane];
    float acc = b1[lane];
    #pragma unroll
    for (int j = 0; j < 64; j++)
        acc = fmaf(__shfl(hl, j, 64), w1T[j * 64 + lane], acc);
    #pragma unroll
    for (int j = 0; j < 64; j++)
        acc = fmaf(__shfl(gl, j, 64), w1T[(64 + j) * 64 + lane], acc);
    z1[(size_t)n * 64 + lane] = acc;
}

// head GEMV 2: 2 nodes per wave, lane = (node half, output feature 0..31)
__global__ void __launch_bounds__(256) k_o2(
        const float* __restrict__ o1v, const float* __restrict__ w2T2,
        const float* __restrict__ b2, float* __restrict__ z2) {
    int tid = threadIdx.x;
    int lane = tid & 63;
    int ho = lane & 31;
    int base = lane & 32;                                // my half's lane base
    int n = blockIdx.x * 8 + (tid >> 5);
    if (n >= NN) return;
    float hl = o1v[(size_t)n * 64 + ho];
    float hh = o1v[(size_t)n * 64 + 32 + ho];
    float acc = b2[ho];
    #pragma unroll
    for (int j = 0; j < 32; j++)
        acc = fmaf(__shfl(hl, base + j, 64), w2T2[j * 32 + ho], acc);
    #pragma unroll
    for (int j = 0; j < 32; j++)
        acc = fmaf(__shfl(hh, base + j, 64), w2T2[(32 + j) * 32 + ho], acc);
    z2[(size_t)n * 32 + ho] = acc;
}

// head GEMV 3: 2 waves per node (jo = 0..127), coalesced w3T rows
__global__ void __launch_bounds__(256) k_o3(
        const float* __restrict__ o2v, const float* __restrict__ w3T,
        const float* __restrict__ b3, float* __restrict__ outp) {
    int gtid = blockIdx.x * 256 + threadIdx.x;           // N*128
    int lane = threadIdx.x & 63;
    int w = gtid >> 6;
    int n = w >> 1;
    int jo = ((w & 1) << 6) + lane;
    if (n >= NN) return;
    float zl = o2v[(size_t)n * 32 + (lane & 31)];
    float acc = b3[jo];
    #pragma unroll
    for (int j = 0; j < 32; j++)
        acc = fmaf(__shfl(zl, j, 64), w3T[j * 128 + jo], acc);
    size_t dsti = (jo < 64) ? ((size_t)n * 64 + jo) : ((size_t)NN * 64 + (size_t)n * 64 + (jo - 64));
    outp[dsti] = acc;                                    // f32 output
}

extern "C" void kernel_launch(void* const* d_in, const int* in_sizes, int n_in,
                              void* d_out, int out_size, void* d_ws, size_t ws_size,
                              hipStream_t stream) {
    const float* x        = (const float*)d_in[0];
    const int* node_type  = (const int*)d_in[1];
    const int* edge_type  = (const int*)d_in[2];
    const int* edge_index = (const int*)d_in[3];
    const int* batch      = (const int*)d_in[4];
    const float* node_emb = (const float*)d_in[5];
    const float* edge_emb = (const float*)d_in[6];
    const float* w_d1 = (const float*)d_in[7];  const float* b_d1 = (const float*)d_in[8];
    const float* g_d1 = (const float*)d_in[9];  const float* be_d1 = (const float*)d_in[10];
    const float* w_d2 = (const float*)d_in[11]; const float* b_d2 = (const float*)d_in[12];
    const float* g_d2 = (const float*)d_in[13]; const float* be_d2 = (const float*)d_in[14];
    const float* g_c1 = (const float*)d_in[15]; const float* be_c1 = (const float*)d_in[16];
    const float* g_c2 = (const float*)d_in[17]; const float* be_c2 = (const float*)d_in[18];
    const float* g_c3 = (const float*)d_in[19]; const float* be_c3 = (const float*)d_in[20];
    const float* w_o1 = (const float*)d_in[21]; const float* b_o1 = (const float*)d_in[22];
    const float* g_o1 = (const float*)d_in[23]; const float* be_o1 = (const float*)d_in[24];
    const float* w_o2 = (const float*)d_in[25]; const float* b_o2 = (const float*)d_in[26];
    const float* g_o2 = (const float*)d_in[27]; const float* be_o2 = (const float*)d_in[28];
    const float* w_o3 = (const float*)d_in[29]; const float* b_o3 = (const float*)d_in[30];
    (void)b_d1;  // cancels inside BN1 (mean subtraction removes per-feature shift)
    const int* src  = edge_index;
    const int* dstv = edge_index + EE;

    char* ws = (char*)d_ws;
    int4*  esd     = (int4*)(ws + OFF_ESD);
    int*   row_ptr = (int*)(ws + OFF_ROWP);
    float* hA   = (float*)(ws + OFF_HA);
    float* hB   = (float*)(ws + OFF_HB);
    float* zb   = (float*)(ws + OFF_ZB);
    float* ytab = (float*)(ws + OFF_YTAB);
    u32*   ptab = (u32*)(ws + OFF_PTAB);
    float* w2T  = (float*)(ws + OFF_W2T);
    float* b2f  = (float*)(ws + OFF_B2F);
    float* Aw   = (float*)(ws + OFF_AW);
    float* Cw   = (float*)(ws + OFF_CW);
    float* mxp  = (float*)(ws + OFF_MX);
    float* sc2  = (float*)(ws + OFF_SC2);
    float* sh2  = (float*)(ws + OFF_SH2);
    int*   psum = (int*)(ws + OFF_PSUM);
    int*   pbase= (int*)(ws + OFF_PBASE);
    float* w1T  = (float*)(ws + OFF_W1T);
    float* w2T2 = (float*)(ws + OFF_W2O);
    float* w3T  = (float*)(ws + OFF_W3T);
    int*   hist   = (int*)(ws + OFF_HIST);
    int*   cursor = (int*)(ws + OFF_CUR);
    float* hg     = (float*)(ws + OFF_HG);
    double* xstat = (double*)(ws + OFF_XSTAT);
    double* sty   = (double*)(ws + OFF_STY);
    double* fst   = (double*)(ws + OFF_FST);
    double* st0 = fst;          double* st1 = fst + 128;  double* st2 = fst + 256;
    double* st3 = fst + 384;    double* st4 = fst + 512;

    hipMemsetAsync(ws + OFF_HIST, 0, ZERO_BYTES, stream);

    k_w2prep<<<16, 256, 0, stream>>>(w_d2, b_d2, w2T, b2f);
    k_otprep<<<56, 256, 0, stream>>>(w_o1, w_o2, w_o3, w1T, w2T2, w3T);
    k_xstats<<<512, 256, 0, stream>>>(x, xstat);
    k_hist<<<NBY, 256, 0, stream>>>(dstv, hist);
    k_scanA<<<256, 256, 0, stream>>>(hist, psum);
    k_scanB<<<1, 256, 0, stream>>>(psum, pbase, row_ptr);
    k_scanC<<<256, 256, 0, stream>>>(hist, pbase, row_ptr);
    k_prep2<<<1, 64, 0, stream>>>(xstat, w_d1, g_d1, be_d1, Aw, Cw, mxp);
    k_ytab<<<(NTB + 1 + 3) / 4, 256, 0, stream>>>(Aw, Cw, mxp, w2T, b2f, ytab);
    k_scatter<<<NBY, 256, 0, stream>>>(x, src, dstv, edge_type, row_ptr, cursor, esd);
    k_ymom<<<1221, 256, 0, stream>>>(x, ytab, sty);
    k_ysc<<<1, 64, 0, stream>>>(sty, g_d2, be_d2, sc2, sh2);
    k_ypack<<<NTB * 64 / 256, 256, 0, stream>>>(ytab, sc2, sh2, ptab);
    // gconv 1 (h from node_emb[node_type], L1-resident)
    k_agg0<<<12500, 256, 0, stream>>>(node_type, node_emb, esd, row_ptr, ptab, edge_emb, hB);
    k_fstats<<<1024, 256, 0, stream>>>(hB, NN, 6, st0);
    k_bn<<<12500, 256, 0, stream>>>(hB, hB, st0, g_c1, be_c1, NN, 6, 1);
    // gconv 2
    k_agg<<<12500, 256, 0, stream>>>(hB, esd, row_ptr, ptab, edge_emb, hA);
    k_fstats<<<1024, 256, 0, stream>>>(hA, NN, 6, st1);
    k_bn<<<12500, 256, 0, stream>>>(hA, hA, st1, g_c2, be_c2, NN, 6, 1);
    // gconv 3 (no activation)
    k_agg<<<12500, 256, 0, stream>>>(hA, esd, row_ptr, ptab, edge_emb, hB);
    k_fstats<<<1024, 256, 0, stream>>>(hB, NN, 6, st2);
    k_bn<<<12500, 256, 0, stream>>>(hB, hB, st2, g_c3, be_c3, NN, 6, 0);
    // global pool + head
    k_hglobal<<<12500, 256, 0, stream>>>(hB, batch, hg);
    k_o1<<<12500, 256, 0, stream>>>(hB, hg, batch, w1T, b_o1, hA);
    k_fstats<<<1024, 256, 0, stream>>>(hA, NN, 6, st3);
    k_bn<<<12500, 256, 0, stream>>>(hA, hA, st3, g_o1, be_o1, NN, 6, 1);
    k_o2<<<6250, 256, 0, stream>>>(hA, w2T2, b_o2, zb);
    k_fstats<<<1024, 256, 0, stream>>>(zb, NN, 5, st4);
    k_bn<<<6250, 256, 0, stream>>>(zb, zb, st4, g_o2, be_o2, NN, 5, 1);
    k_o3<<<25000, 256, 0, stream>>>(zb, w3T, b_o3, (float*)d_out);
    (void)in_sizes; (void)n_in; (void)out_size; (void)ws_size;
}

// Round 10
// 870.526 us; speedup vs baseline: 2.2262x; 1.0739x over previous
//
#include <hip/hip_runtime.h>
#include <stdint.h>

#define NN 50000
#define EE 1250000
#define BB 500
#define NBY 4883      // ceil(EE/256)
#define CHUNK 196     // ceil(NN/256) for scan partitions
#define BN_EPS 1e-5f

#define NTB 8192      // table intervals; 8193 knots
#define XLO (-12.0f)
#define XHI (12.0f)
#define XSC ((float)NTB / (XHI - XLO))   // knots at XLO + i/XSC
#define DXT ((XHI - XLO) / (float)NTB)
#define TPMAX 8191.999f

using u16 = unsigned short;
using u32 = unsigned int;

__device__ __forceinline__ float bf2f(u16 v) { return __uint_as_float(((u32)v) << 16); }
__device__ __forceinline__ u16 f2bf(float f) {
    u32 u = __float_as_uint(f);
    return (u16)((u + 0x7fffu + ((u >> 16) & 1u)) >> 16);
}
__device__ __forceinline__ u32 pk2(float a, float b) { return (u32)f2bf(a) | ((u32)f2bf(b) << 16); }
// softplus via native v_exp_f32 / v_log_f32 (R9: __expf/__logf lowered to multi-instr OCML)
__device__ __forceinline__ float sp(float z) {
    float t = __builtin_amdgcn_exp2f(-fabsf(z) * 1.44269504f);
    float l = __builtin_amdgcn_logf(1.f + t) * 0.69314718f;
    return fmaxf(z, 0.f) + l;
}

// ---------------- workspace layout (~65 MB) ----------------
constexpr size_t OFF_ESD  = 0;                                    // int4 [E] {src, et, i, f_bits}
constexpr size_t OFF_ROWP = OFF_ESD + (size_t)EE * 16;            // row_ptr [N+1]
constexpr size_t OFF_HA   = (OFF_ROWP + (size_t)(NN + 1) * 4 + 255) & ~(size_t)255;
constexpr size_t OFF_HB   = OFF_HA + (size_t)NN * 64 * 4;
constexpr size_t OFF_ZB   = OFF_HB + (size_t)NN * 64 * 4;         // [N,32]
constexpr size_t OFF_YTAB = OFF_ZB + (size_t)NN * 32 * 4;         // f32 [NTB+1][64]
constexpr size_t OFF_PTAB = OFF_YTAB + (size_t)(NTB + 1) * 64 * 4;// u32 [NTB][64] bf16 pairs (affined)
constexpr size_t OFF_W2T  = OFF_PTAB + (size_t)NTB * 64 * 4;      // w_d2 transposed f32 [64][64]
constexpr size_t OFF_B2F  = OFF_W2T + 4096 * 4;
constexpr size_t OFF_AW   = OFF_B2F + 256;
constexpr size_t OFF_CW   = OFF_AW + 256;
constexpr size_t OFF_MX   = OFF_CW + 256;
constexpr size_t OFF_SC2  = OFF_MX + 256;
constexpr size_t OFF_SH2  = OFF_SC2 + 256;
constexpr size_t OFF_PSUM = OFF_SH2 + 256;                        // [256] int
constexpr size_t OFF_PBASE= OFF_PSUM + 1024;                      // [256] int
constexpr size_t OFF_W1T  = OFF_PBASE + 1024;                     // f32 [128][64] (w_o1^T)
constexpr size_t OFF_W2O  = OFF_W1T + 8192 * 4;                   // f32 [64][32]  (w_o2^T)
constexpr size_t OFF_W3T  = OFF_W2O + 2048 * 4;                   // f32 [32][128] (w_o3^T)
constexpr size_t OFF_BPTR = OFF_W3T + 4096 * 4;                   // int [B+1]
// zero region (one memset): hist | cursor | hg | xstat | sty | 5 stat slots
constexpr size_t OFF_HIST = (OFF_BPTR + (BB + 1) * 4 + 255) & ~(size_t)255;
constexpr size_t OFF_CUR  = OFF_HIST + (size_t)NN * 4;
constexpr size_t OFF_HG   = OFF_CUR + (size_t)NN * 4;
constexpr size_t OFF_XSTAT= OFF_HG + (size_t)BB * 64 * 4;         // 2 doubles
constexpr size_t OFF_STY  = OFF_XSTAT + 16;                       // 128 doubles
constexpr size_t OFF_FST  = OFF_STY + 128 * 8;
constexpr size_t ZERO_END = OFF_FST + 5 * 128 * 8;
constexpr size_t ZERO_BYTES = ZERO_END - OFF_HIST;

// ---------------- prep kernels ----------------
__global__ void k_w2prep(const float* __restrict__ w2, const float* __restrict__ b2,
                         float* __restrict__ w2T, float* __restrict__ b2f) {
    int idx = blockIdx.x * 256 + threadIdx.x;            // 4096
    int hin = idx >> 6, ho = idx & 63;
    w2T[idx] = w2[ho * 64 + hin];
    if (idx < 64) b2f[idx] = b2[idx];
}

__global__ void k_otprep(const float* __restrict__ w1, const float* __restrict__ w2,
                         const float* __restrict__ w3, float* __restrict__ w1T,
                         float* __restrict__ w2T2, float* __restrict__ w3T) {
    int idx = blockIdx.x * 256 + threadIdx.x;            // 14336
    if (idx < 8192) {
        int j = idx >> 6, ho = idx & 63;
        w1T[idx] = w1[ho * 128 + j];
    } else if (idx < 8192 + 2048) {
        int t = idx - 8192;
        int j = t >> 5, ho = t & 31;
        w2T2[t] = w2[ho * 64 + j];
    } else if (idx < 8192 + 2048 + 4096) {
        int t = idx - 8192 - 2048;
        int j = t >> 7, jo = t & 127;
        w3T[t] = w3[jo * 32 + j];
    }
}

__global__ void k_xstats(const float* __restrict__ x, double* __restrict__ xstat) {
    __shared__ float ls[256], lq[256];
    float s = 0, q = 0;
    for (int i = blockIdx.x * 256 + threadIdx.x; i < EE; i += gridDim.x * 256) {
        float v = x[i]; s += v; q += v * v;
    }
    ls[threadIdx.x] = s; lq[threadIdx.x] = q; __syncthreads();
    for (int off = 128; off > 0; off >>= 1) {
        if (threadIdx.x < off) { ls[threadIdx.x] += ls[threadIdx.x + off]; lq[threadIdx.x] += lq[threadIdx.x + off]; }
        __syncthreads();
    }
    if (threadIdx.x == 0) { atomicAdd(&xstat[0], (double)ls[0]); atomicAdd(&xstat[1], (double)lq[0]); }
}

__global__ void k_hist(const int* __restrict__ dstv, int* __restrict__ hist) {
    int e = blockIdx.x * 256 + threadIdx.x;
    if (e < EE) atomicAdd(&hist[dstv[e]], 1);
}

// batch is sorted -> segment pointers for global pooling (replaces f32-CAS k_hglobal)
__global__ void k_bptr(const int* __restrict__ batch, int* __restrict__ bptr) {
    int n = blockIdx.x * 256 + threadIdx.x;
    if (n >= NN) return;
    int b = batch[n];
    int pb = (n == 0) ? -1 : batch[n - 1];
    for (int k = pb + 1; k <= b; k++) bptr[k] = n;
    if (n == NN - 1) { for (int k = b + 1; k <= BB; k++) bptr[k] = NN; }
}

__global__ void k_scanA(const int* __restrict__ hist, int* __restrict__ psum) {
    __shared__ int ls[256];
    int t = threadIdx.x, idx = blockIdx.x * CHUNK + t;
    ls[t] = (t < CHUNK && idx < NN) ? hist[idx] : 0; __syncthreads();
    for (int off = 128; off > 0; off >>= 1) {
        if (t < off) ls[t] += ls[t + off];
        __syncthreads();
    }
    if (t == 0) psum[blockIdx.x] = ls[0];
}

__global__ void k_scanB(const int* __restrict__ psum, int* __restrict__ pbase, int* __restrict__ row_ptr) {
    __shared__ int ls[256];
    int t = threadIdx.x, v = psum[t];
    ls[t] = v; __syncthreads();
    for (int off = 1; off < 256; off <<= 1) {
        int a = ls[t]; int b = (t >= off) ? ls[t - off] : 0; __syncthreads();
        ls[t] = a + b; __syncthreads();
    }
    pbase[t] = ls[t] - v;
    if (t == 0) row_ptr[NN] = EE;
}

__global__ void k_scanC(const int* __restrict__ hist, const int* __restrict__ pbase, int* __restrict__ row_ptr) {
    __shared__ int ls[256];
    int t = threadIdx.x, idx = blockIdx.x * CHUNK + t;
    int v = (t < CHUNK && idx < NN) ? hist[idx] : 0;
    ls[t] = v; __syncthreads();
    for (int off = 1; off < 256; off <<= 1) {
        int a = ls[t]; int b = (t >= off) ? ls[t - off] : 0; __syncthreads();
        ls[t] = a + b; __syncthreads();
    }
    if (t < CHUNK && idx < NN) row_ptr[idx] = pbase[blockIdx.x] + ls[t] - v;
}

__global__ void k_prep2(const double* __restrict__ xstat, const float* __restrict__ w1,
                        const float* __restrict__ g1, const float* __restrict__ be1,
                        float* __restrict__ Aw, float* __restrict__ Cw, float* __restrict__ mxp) {
    int f = threadIdx.x;  // 64
    double mx = xstat[0] / (double)EE;
    double vx = xstat[1] / (double)EE - mx * mx; if (vx < 0) vx = 0;
    float w = w1[f];
    Aw[f] = w * rsqrtf((float)vx * w * w + BN_EPS) * g1[f];
    Cw[f] = be1[f];
    if (f == 0) mxp[0] = (float)mx;
}

// build y(x) table: wave-per-knot, lane = output feature; d1 via shuffle broadcast
__global__ void __launch_bounds__(256) k_ytab(
        const float* __restrict__ Aw, const float* __restrict__ Cw, const float* __restrict__ mxp,
        const float* __restrict__ w2T, const float* __restrict__ b2f, float* __restrict__ ytab) {
    int lane = threadIdx.x & 63;
    int idx = blockIdx.x * 4 + (threadIdx.x >> 6);       // knot id
    if (idx > NTB) return;
    float xi = XLO + (float)idx * DXT;
    float t = xi - mxp[0];
    float d1L = sp(fmaf(Aw[lane], t, Cw[lane]));
    float y = b2f[lane];
    #pragma unroll
    for (int hin = 0; hin < 64; hin++) {
        float d1 = __shfl(d1L, hin, 64);
        y = fmaf(d1, w2T[hin * 64 + lane], y);
    }
    ytab[(idx << 6) | lane] = y;
}

// BN2 moments: dense scan of all E edges through the f32 table, lane = feature, unroll-4
__device__ __forceinline__ void ymom_edge(float xv, const float* __restrict__ ytab, int lane,
                                          float& s, float& q) {
    float tp = fminf(fmaxf((xv - XLO) * XSC, 0.f), TPMAX);
    int i = (int)tp; float f = tp - (float)i;
    float a = ytab[(i << 6) | lane];
    float b = ytab[((i + 1) << 6) | lane];
    float y = fmaf(f, b - a, a);
    s += y; q += y * y;
}

__global__ void __launch_bounds__(256) k_ymom(
        const float* __restrict__ x, const float* __restrict__ ytab, double* __restrict__ sty) {
    int lane = threadIdx.x & 63;
    int wid = (blockIdx.x * 256 + threadIdx.x) >> 6;     // 4884 waves (1221 blocks)
    float s = 0, q = 0;
    int e0 = wid * 256;
    int e1 = e0 + 256; if (e1 > EE) e1 = EE;
    int p = e0;
    for (; p + 4 <= e1; p += 4) {
        float x0 = x[p], x1 = x[p + 1], x2 = x[p + 2], x3 = x[p + 3];
        ymom_edge(x0, ytab, lane, s, q);
        ymom_edge(x1, ytab, lane, s, q);
        ymom_edge(x2, ytab, lane, s, q);
        ymom_edge(x3, ytab, lane, s, q);
    }
    for (; p < e1; ++p) ymom_edge(x[p], ytab, lane, s, q);
    __shared__ float lsS[256], lsQ[256];
    lsS[threadIdx.x] = s; lsQ[threadIdx.x] = q; __syncthreads();
    if (threadIdx.x < 128) {
        int ff = threadIdx.x & 63; bool isq = threadIdx.x >= 64;
        float acc = 0;
        #pragma unroll
        for (int j = 0; j < 4; j++) acc += isq ? lsQ[j * 64 + ff] : lsS[j * 64 + ff];
        atomicAdd(&sty[threadIdx.x], (double)acc);
    }
}

__global__ void k_ysc(const double* __restrict__ sty, const float* __restrict__ g2,
                      const float* __restrict__ be2, float* __restrict__ sc2, float* __restrict__ sh2) {
    int f = threadIdx.x;  // 64
    double m = sty[f] / (double)EE;
    double var = sty[64 + f] / (double)EE - m * m; if (var < 0) var = 0;
    float rstd = rsqrtf((float)var + BN_EPS);
    float sc = rstd * g2[f];
    sc2[f] = sc;
    sh2[f] = be2[f] - (float)m * sc;
}

__global__ void k_ypack(const float* __restrict__ ytab, const float* __restrict__ sc2,
                        const float* __restrict__ sh2, u32* __restrict__ ptab) {
    int tid = blockIdx.x * 256 + threadIdx.x;            // NTB*64
    int f = tid & 63;
    float sc = sc2[f], sh = sh2[f];
    float a = fmaf(ytab[tid], sc, sh);
    float b = fmaf(ytab[tid + 64], sc, sh);
    ptab[tid] = pk2(a, b);
}

// counting-sort edges: write packed {src, et, i, f} (table coord precomputed once)
__global__ void __launch_bounds__(256) k_scatter(
        const float* __restrict__ x, const int* __restrict__ src, const int* __restrict__ dstv,
        const int* __restrict__ etv, const int* __restrict__ row_ptr, int* __restrict__ cursor,
        int4* __restrict__ esd) {
    int e = blockIdx.x * 256 + threadIdx.x;
    if (e >= EE) return;
    int d = dstv[e];
    int p = row_ptr[d] + atomicAdd(&cursor[d], 1);
    float tp = fminf(fmaxf((x[e] - XLO) * XSC, 0.f), TPMAX);
    int i = (int)tp; float f = tp - (float)i;
    int4 v; v.x = src[e]; v.y = etv[e]; v.z = i; v.w = __float_as_int(f);
    esd[p] = v;
}

// per-edge term: precomputed (i,f), 32-bit saddr indexing, direct bf16 unpack
__device__ __forceinline__ float edge_term(int4 ed, int lane, const u32* __restrict__ ptab,
                                           const float* __restrict__ emb) {
    u32 pr = ptab[(ed.z << 6) | lane];
    float f = __int_as_float(ed.w);
    float a = __uint_as_float(pr << 16);
    float b = __uint_as_float(pr & 0xffff0000u);
    float y = fmaf(f, b - a, a);
    return y * emb[(ed.y << 6) | lane];
}

// wave-per-node aggregation, lane = feature; generic h input; unroll-4
__global__ void __launch_bounds__(256) k_agg(
        const float* __restrict__ h, const int4* __restrict__ esd, const int* __restrict__ row_ptr,
        const u32* __restrict__ ptab, const float* __restrict__ emb, float* __restrict__ hpre) {
    int lane = threadIdx.x & 63;
    int n = __builtin_amdgcn_readfirstlane((int)(blockIdx.x * 4 + (threadIdx.x >> 6)));
    if (n >= NN) return;
    int p0 = row_ptr[n], p1 = row_ptr[n + 1];
    float acc = 0.f;
    int p = p0;
    for (; p + 4 <= p1; p += 4) {
        int4 e0 = esd[p], e1 = esd[p + 1], e2 = esd[p + 2], e3 = esd[p + 3];
        float h0 = h[(e0.x << 6) | lane];
        float h1 = h[(e1.x << 6) | lane];
        float h2 = h[(e2.x << 6) | lane];
        float h3 = h[(e3.x << 6) | lane];
        float a0 = edge_term(e0, lane, ptab, emb);
        float a1 = edge_term(e1, lane, ptab, emb);
        float a2 = edge_term(e2, lane, ptab, emb);
        float a3 = edge_term(e3, lane, ptab, emb);
        acc += sp(h0 + a0) + sp(h1 + a1) + sp(h2 + a2) + sp(h3 + a3);
    }
    for (; p < p1; ++p) {
        int4 e0 = esd[p];
        float h0 = h[(e0.x << 6) | lane];
        acc += sp(h0 + edge_term(e0, lane, ptab, emb));
    }
    int o = (n << 6) | lane;
    hpre[o] = acc + h[o];
}

// gconv1 variant: h comes from node_emb[node_type] (L1-resident)
__global__ void __launch_bounds__(256) k_agg0(
        const int* __restrict__ nt, const float* __restrict__ nemb, const int4* __restrict__ esd,
        const int* __restrict__ row_ptr, const u32* __restrict__ ptab,
        const float* __restrict__ emb, float* __restrict__ hpre) {
    int lane = threadIdx.x & 63;
    int n = __builtin_amdgcn_readfirstlane((int)(blockIdx.x * 4 + (threadIdx.x >> 6)));
    if (n >= NN) return;
    int p0 = row_ptr[n], p1 = row_ptr[n + 1];
    float acc = 0.f;
    int p = p0;
    for (; p + 4 <= p1; p += 4) {
        int4 e0 = esd[p], e1 = esd[p + 1], e2 = esd[p + 2], e3 = esd[p + 3];
        float h0 = nemb[(nt[e0.x] << 6) | lane];
        float h1 = nemb[(nt[e1.x] << 6) | lane];
        float h2 = nemb[(nt[e2.x] << 6) | lane];
        float h3 = nemb[(nt[e3.x] << 6) | lane];
        float a0 = edge_term(e0, lane, ptab, emb);
        float a1 = edge_term(e1, lane, ptab, emb);
        float a2 = edge_term(e2, lane, ptab, emb);
        float a3 = edge_term(e3, lane, ptab, emb);
        acc += sp(h0 + a0) + sp(h1 + a1) + sp(h2 + a2) + sp(h3 + a3);
    }
    for (; p < p1; ++p) {
        int4 e0 = esd[p];
        float h0 = nemb[(nt[e0.x] << 6) | lane];
        acc += sp(h0 + edge_term(e0, lane, ptab, emb));
    }
    hpre[(n << 6) | lane] = acc + nemb[(nt[n] << 6) | lane];
}

// per-feature mean/var partials over [rows, C] (C = 1<<logC), f64 atomics
__global__ void k_fstats(const float* __restrict__ v, int rows, int logC, double* __restrict__ stat) {
    int C = 1 << logC;
    int f = threadIdx.x & (C - 1);
    int r0 = threadIdx.x >> logC;
    int rpb = 256 >> logC;
    float s = 0, q = 0;
    for (int r = blockIdx.x * rpb + r0; r < rows; r += gridDim.x * rpb) {
        float val = v[(size_t)r * C + f];
        s += val; q += val * val;
    }
    __shared__ float lsS[256], lsQ[256];
    lsS[threadIdx.x] = s; lsQ[threadIdx.x] = q; __syncthreads();
    if (threadIdx.x < C) {
        float ss = 0, qq = 0;
        for (int j = 0; j < rpb; j++) { ss += lsS[j * C + threadIdx.x]; qq += lsQ[j * C + threadIdx.x]; }
        atomicAdd(&stat[threadIdx.x], (double)ss);
        atomicAdd(&stat[C + threadIdx.x], (double)qq);
    }
}

__global__ void k_bn(const float* __restrict__ in, float* __restrict__ out,
                     const double* __restrict__ stat, const float* __restrict__ g,
                     const float* __restrict__ be, int rows, int logC, int act) {
    int C = 1 << logC;
    size_t total = (size_t)rows << logC;
    size_t i = (size_t)blockIdx.x * 256 + threadIdx.x;
    if (i >= total) return;
    int f = (int)(i & (C - 1));
    double m = stat[f] / (double)rows;
    double var = stat[C + f] / (double)rows - m * m; if (var < 0) var = 0;
    float rstd = rsqrtf((float)var + BN_EPS);
    float val = (in[i] - (float)m) * rstd * g[f] + be[f];
    out[i] = act ? sp(val) : val;
}

// global pooling: block-per-batch segment sum over sorted batch (no atomics)
__global__ void __launch_bounds__(256) k_hg2(
        const float* __restrict__ h, const int* __restrict__ bptr, float* __restrict__ hg) {
    int b = blockIdx.x;                                  // BB
    int lane = threadIdx.x & 63, w = threadIdx.x >> 6;
    int n0 = bptr[b], n1 = bptr[b + 1];
    float acc = 0.f;
    for (int n = n0 + w; n < n1; n += 4)
        acc += h[(n << 6) | lane];
    __shared__ float ls[256];
    ls[threadIdx.x] = acc; __syncthreads();
    if (threadIdx.x < 64)
        hg[(b << 6) | lane] = ls[lane] + ls[64 + lane] + ls[128 + lane] + ls[192 + lane];
}

// head GEMV 1: lane = output feature; coalesced w1T rows; input broadcast via shfl
__global__ void __launch_bounds__(256) k_o1(
        const float* __restrict__ h, const float* __restrict__ hg, const int* __restrict__ batch,
        const float* __restrict__ w1T, const float* __restrict__ b1, float* __restrict__ z1) {
    int lane = threadIdx.x & 63;
    int n = __builtin_amdgcn_readfirstlane((int)(blockIdx.x * 4 + (threadIdx.x >> 6)));
    if (n >= NN) return;
    int b = batch[n];
    float hl = h[(n << 6) | lane];
    float gl = hg[(b << 6) | lane];
    float acc = b1[lane], acc2 = 0.f;
    #pragma unroll
    for (int j = 0; j < 64; j += 2) {
        acc  = fmaf(__shfl(hl, j, 64),     w1T[(j << 6) | lane], acc);
        acc2 = fmaf(__shfl(hl, j + 1, 64), w1T[((j + 1) << 6) | lane], acc2);
    }
    #pragma unroll
    for (int j = 0; j < 64; j += 2) {
        acc  = fmaf(__shfl(gl, j, 64),     w1T[((64 + j) << 6) | lane], acc);
        acc2 = fmaf(__shfl(gl, j + 1, 64), w1T[((65 + j) << 6) | lane], acc2);
    }
    z1[(n << 6) | lane] = acc + acc2;
}

// head GEMV 2: 2 nodes per wave, lane = (node half, output feature 0..31)
__global__ void __launch_bounds__(256) k_o2(
        const float* __restrict__ o1v, const float* __restrict__ w2T2,
        const float* __restrict__ b2, float* __restrict__ z2) {
    int tid = threadIdx.x;
    int lane = tid & 63;
    int ho = lane & 31;
    int base = lane & 32;
    int n = blockIdx.x * 8 + (tid >> 5);
    if (n >= NN) return;
    float hl = o1v[(n << 6) | ho];
    float hh = o1v[(n << 6) | (32 + ho)];
    float acc = b2[ho];
    #pragma unroll
    for (int j = 0; j < 32; j++)
        acc = fmaf(__shfl(hl, base + j, 64), w2T2[(j << 5) | ho], acc);
    #pragma unroll
    for (int j = 0; j < 32; j++)
        acc = fmaf(__shfl(hh, base + j, 64), w2T2[((32 + j) << 5) | ho], acc);
    z2[(n << 5) | ho] = acc;
}

// head GEMV 3: 2 waves per node (jo = 0..127), coalesced w3T rows
__global__ void __launch_bounds__(256) k_o3(
        const float* __restrict__ o2v, const float* __restrict__ w3T,
        const float* __restrict__ b3, float* __restrict__ outp) {
    int gtid = blockIdx.x * 256 + threadIdx.x;           // N*128
    int lane = threadIdx.x & 63;
    int w = gtid >> 6;
    int n = w >> 1;
    int jo = ((w & 1) << 6) + lane;
    if (n >= NN) return;
    float zl = o2v[(n << 5) | (lane & 31)];
    float acc = b3[jo];
    #pragma unroll
    for (int j = 0; j < 32; j++)
        acc = fmaf(__shfl(zl, j, 64), w3T[(j << 7) | jo], acc);
    size_t dsti = (jo < 64) ? ((size_t)(n << 6) + jo) : ((size_t)NN * 64 + (size_t)(n << 6) + (jo - 64));
    outp[dsti] = acc;                                    // f32 output
}

extern "C" void kernel_launch(void* const* d_in, const int* in_sizes, int n_in,
                              void* d_out, int out_size, void* d_ws, size_t ws_size,
                              hipStream_t stream) {
    const float* x        = (const float*)d_in[0];
    const int* node_type  = (const int*)d_in[1];
    const int* edge_type  = (const int*)d_in[2];
    const int* edge_index = (const int*)d_in[3];
    const int* batch      = (const int*)d_in[4];
    const float* node_emb = (const float*)d_in[5];
    const float* edge_emb = (const float*)d_in[6];
    const float* w_d1 = (const float*)d_in[7];  const float* b_d1 = (const float*)d_in[8];
    const float* g_d1 = (const float*)d_in[9];  const float* be_d1 = (const float*)d_in[10];
    const float* w_d2 = (const float*)d_in[11]; const float* b_d2 = (const float*)d_in[12];
    const float* g_d2 = (const float*)d_in[13]; const float* be_d2 = (const float*)d_in[14];
    const float* g_c1 = (const float*)d_in[15]; const float* be_c1 = (const float*)d_in[16];
    const float* g_c2 = (const float*)d_in[17]; const float* be_c2 = (const float*)d_in[18];
    const float* g_c3 = (const float*)d_in[19]; const float* be_c3 = (const float*)d_in[20];
    const float* w_o1 = (const float*)d_in[21]; const float* b_o1 = (const float*)d_in[22];
    const float* g_o1 = (const float*)d_in[23]; const float* be_o1 = (const float*)d_in[24];
    const float* w_o2 = (const float*)d_in[25]; const float* b_o2 = (const float*)d_in[26];
    const float* g_o2 = (const float*)d_in[27]; const float* be_o2 = (const float*)d_in[28];
    const float* w_o3 = (const float*)d_in[29]; const float* b_o3 = (const float*)d_in[30];
    (void)b_d1;  // cancels inside BN1 (mean subtraction removes per-feature shift)
    const int* src  = edge_index;
    const int* dstv = edge_index + EE;

    char* ws = (char*)d_ws;
    int4*  esd     = (int4*)(ws + OFF_ESD);
    int*   row_ptr = (int*)(ws + OFF_ROWP);
    float* hA   = (float*)(ws + OFF_HA);
    float* hB   = (float*)(ws + OFF_HB);
    float* zb   = (float*)(ws + OFF_ZB);
    float* ytab = (float*)(ws + OFF_YTAB);
    u32*   ptab = (u32*)(ws + OFF_PTAB);
    float* w2T  = (float*)(ws + OFF_W2T);
    float* b2f  = (float*)(ws + OFF_B2F);
    float* Aw   = (float*)(ws + OFF_AW);
    float* Cw   = (float*)(ws + OFF_CW);
    float* mxp  = (float*)(ws + OFF_MX);
    float* sc2  = (float*)(ws + OFF_SC2);
    float* sh2  = (float*)(ws + OFF_SH2);
    int*   psum = (int*)(ws + OFF_PSUM);
    int*   pbase= (int*)(ws + OFF_PBASE);
    float* w1T  = (float*)(ws + OFF_W1T);
    float* w2T2 = (float*)(ws + OFF_W2O);
    float* w3T  = (float*)(ws + OFF_W3T);
    int*   bptr = (int*)(ws + OFF_BPTR);
    int*   hist   = (int*)(ws + OFF_HIST);
    int*   cursor = (int*)(ws + OFF_CUR);
    float* hg     = (float*)(ws + OFF_HG);
    double* xstat = (double*)(ws + OFF_XSTAT);
    double* sty   = (double*)(ws + OFF_STY);
    double* fst   = (double*)(ws + OFF_FST);
    double* st0 = fst;          double* st1 = fst + 128;  double* st2 = fst + 256;
    double* st3 = fst + 384;    double* st4 = fst + 512;

    hipMemsetAsync(ws + OFF_HIST, 0, ZERO_BYTES, stream);

    k_w2prep<<<16, 256, 0, stream>>>(w_d2, b_d2, w2T, b2f);
    k_otprep<<<56, 256, 0, stream>>>(w_o1, w_o2, w_o3, w1T, w2T2, w3T);
    k_xstats<<<512, 256, 0, stream>>>(x, xstat);
    k_hist<<<NBY, 256, 0, stream>>>(dstv, hist);
    k_bptr<<<196, 256, 0, stream>>>(batch, bptr);
    k_scanA<<<256, 256, 0, stream>>>(hist, psum);
    k_scanB<<<1, 256, 0, stream>>>(psum, pbase, row_ptr);
    k_scanC<<<256, 256, 0, stream>>>(hist, pbase, row_ptr);
    k_prep2<<<1, 64, 0, stream>>>(xstat, w_d1, g_d1, be_d1, Aw, Cw, mxp);
    k_ytab<<<(NTB + 1 + 3) / 4, 256, 0, stream>>>(Aw, Cw, mxp, w2T, b2f, ytab);
    k_scatter<<<NBY, 256, 0, stream>>>(x, src, dstv, edge_type, row_ptr, cursor, esd);
    k_ymom<<<1221, 256, 0, stream>>>(x, ytab, sty);
    k_ysc<<<1, 64, 0, stream>>>(sty, g_d2, be_d2, sc2, sh2);
    k_ypack<<<NTB * 64 / 256, 256, 0, stream>>>(ytab, sc2, sh2, ptab);
    // gconv 1 (h from node_emb[node_type], L1-resident)
    k_agg0<<<12500, 256, 0, stream>>>(node_type, node_emb, esd, row_ptr, ptab, edge_emb, hB);
    k_fstats<<<1024, 256, 0, stream>>>(hB, NN, 6, st0);
    k_bn<<<12500, 256, 0, stream>>>(hB, hB, st0, g_c1, be_c1, NN, 6, 1);
    // gconv 2
    k_agg<<<12500, 256, 0, stream>>>(hB, esd, row_ptr, ptab, edge_emb, hA);
    k_fstats<<<1024, 256, 0, stream>>>(hA, NN, 6, st1);
    k_bn<<<12500, 256, 0, stream>>>(hA, hA, st1, g_c2, be_c2, NN, 6, 1);
    // gconv 3 (no activation)
    k_agg<<<12500, 256, 0, stream>>>(hA, esd, row_ptr, ptab, edge_emb, hB);
    k_fstats<<<1024, 256, 0, stream>>>(hB, NN, 6, st2);
    k_bn<<<12500, 256, 0, stream>>>(hB, hB, st2, g_c3, be_c3, NN, 6, 0);
    // global pool + head
    k_hg2<<<BB, 256, 0, stream>>>(hB, bptr, hg);
    k_o1<<<12500, 256, 0, stream>>>(hB, hg, batch, w1T, b_o1, hA);
    k_fstats<<<1024, 256, 0, stream>>>(hA, NN, 6, st3);
    k_bn<<<12500, 256, 0, stream>>>(hA, hA, st3, g_o1, be_o1, NN, 6, 1);
    k_o2<<<6250, 256, 0, stream>>>(hA, w2T2, b_o2, zb);
    k_fstats<<<1024, 256, 0, stream>>>(zb, NN, 5, st4);
    k_bn<<<6250, 256, 0, stream>>>(zb, zb, st4, g_o2, be_o2, NN, 5, 1);
    k_o3<<<25000, 256, 0, stream>>>(zb, w3T, b_o3, (float*)d_out);
    (void)in_sizes; (void)n_in; (void)out_size; (void)ws_size;
}